// Round 9
// baseline (226.284 us; speedup 1.0000x reference)
//
#include <hip/hip_runtime.h>
#include <hip/hip_bf16.h>

#define B_N 256
#define L_Q 64
#define FEAT_N 2048
#define UNITS_N 512
#define EMB_N 256
#define VOCAB_N 32000

typedef __attribute__((ext_vector_type(8))) short bf16x8;
typedef __attribute__((ext_vector_type(4))) float f32x4;

__device__ __forceinline__ unsigned short f2bf(float x) {
  union { float f; unsigned int u; } c; c.f = x;
  unsigned int u = c.u + 0x7FFFu + ((c.u >> 16) & 1u);
  return (unsigned short)(u >> 16);
}

__device__ __forceinline__ float sigmoidf_(float x) { return 1.0f / (1.0f + __expf(-x)); }

// A-fragment layout for mfma_f32_16x16x32_bf16 (KS = K/32):
//   ushort index = ((rt*KS + ks)*64 + (lq*16+lr))*8 + j ; row = rt*16+lr, k = ks*32+lq*8+j
__device__ __forceinline__ void store_frag4(unsigned short* base, int KS, int row, int k0,
                                            float a, float b, float c, float d) {
  int rt = row >> 4, lr = row & 15;
  int ks = k0 >> 5, lq = (k0 >> 3) & 3, j0 = k0 & 7;
  union { unsigned long long u; unsigned short s[4]; } p;
  p.s[0] = f2bf(a); p.s[1] = f2bf(b); p.s[2] = f2bf(c); p.s[3] = f2bf(d);
  *reinterpret_cast<unsigned long long*>(base + (((rt * KS + ks) * 64) + (lq * 16 + lr)) * 8 + j0) = p.u;
}

// B-fragment weight layout: idx = (((nt*4+ct)*KS + ks)*64 + l)*8 + j
__device__ __forceinline__ void wfrag_one(const float* __restrict__ W, int N, int KS,
                                          unsigned short* __restrict__ dst, int tid, int gruMap) {
  int l = tid & 63;
  int ks = (tid >> 6) % KS;
  int cts = tid / (64 * KS);
  int ct = cts & 3, nt = cts >> 2;
  int nb = gruMap ? (nt < 8 ? nt * 64 : 1024 + (nt - 8) * 64) : nt * 64;
  int ncol = nb + ct * 16 + (l & 15);
  int k0 = ks * 32 + (l >> 4) * 8;
  union { bf16x8 v; unsigned short s[8]; } fr;
#pragma unroll
  for (int j = 0; j < 8; ++j) fr.s[j] = f2bf(W[(size_t)(k0 + j) * N + ncol]);
  *reinterpret_cast<bf16x8*>(dst + (size_t)tid * 8) = fr.v;
}

// ---- fused prep
__global__ void k_prep_all(const float* __restrict__ W1, unsigned short* __restrict__ W1s,
                           const float* __restrict__ hidden,
                           const float* __restrict__ emb_table,
                           const int* __restrict__ tok,
                           unsigned short* __restrict__ hfrag,
                           unsigned short* __restrict__ xinfrag,
                           const float* __restrict__ W2, unsigned short* __restrict__ W2f,
                           const float* __restrict__ W3, unsigned short* __restrict__ W3f,
                           const float* __restrict__ gruK, unsigned short* __restrict__ gruf,
                           const float* __restrict__ fc1W, unsigned short* __restrict__ fc1f) {
  int bb = blockIdx.x;
  if (bb < 512) {
    int t = bb * 256 + threadIdx.x;
    int l = t & 63;
    int c = (t >> 6) & 31;
    int kt = t >> 11;
    int n = c * 16 + (l & 15);
    int k0 = kt * 32 + (l >> 4) * 8;
    union { bf16x8 v; unsigned short s[8]; } fr;
#pragma unroll
    for (int j = 0; j < 8; ++j) fr.s[j] = f2bf(W1[(size_t)(k0 + j) * UNITS_N + n]);
    *reinterpret_cast<bf16x8*>(W1s + (size_t)t * 8) = fr.v;
  } else if (bb < 704) {
    int t = (bb - 512) * 256 + threadIdx.x;
    if (t < 32768) {
      int b = t >> 7, k0 = (t & 127) * 4;
      const float* s = hidden + (size_t)b * UNITS_N + k0;
      store_frag4(hfrag, 16, b, k0, s[0], s[1], s[2], s[3]);
    } else if (t < 49152) {
      int t2 = t - 32768;
      int b = t2 >> 6, e0 = (t2 & 63) * 4;
      const float* s = emb_table + (size_t)tok[b] * EMB_N + e0;
      store_frag4(xinfrag, 24, b, 512 + e0, s[0], s[1], s[2], s[3]);
    }
  } else if (bb < 832) {
    wfrag_one(W2, 512, 16, W2f, (bb - 704) * 256 + threadIdx.x, 0);
  } else if (bb < 1472) {
    wfrag_one(W3, 512, 80, W3f, (bb - 832) * 256 + threadIdx.x, 0);
  } else if (bb < 1856) {
    wfrag_one(gruK, 1536, 24, gruf, (bb - 1472) * 256 + threadIdx.x, 1);
  } else {
    wfrag_one(fc1W, 512, 16, fc1f, (bb - 1856) * 256 + threadIdx.x, 0);
  }
}

// ---- split-K small GEMM (unchanged, proven)
template <int MODE>
__launch_bounds__(256)
__global__ void k_small2(const unsigned short* __restrict__ Afrag, int KS,
                         const unsigned short* __restrict__ Bfrag,
                         const float* __restrict__ bias,
                         float* __restrict__ outF, int N,
                         unsigned short* __restrict__ outFrag, int KSo) {
  constexpr int NCT = (MODE == 2) ? 8 : 4;
  __shared__ f32x4 red[4][2][NCT][64];
  int t = threadIdx.x, w = t >> 6, l = t & 63;
  int nt = blockIdx.x;
  int mb = blockIdx.y;
  int KSq = KS >> 2;

  f32x4 acc[2][NCT];
#pragma unroll
  for (int rt = 0; rt < 2; ++rt)
#pragma unroll
    for (int ct = 0; ct < NCT; ++ct) acc[rt][ct] = (f32x4){0.f, 0.f, 0.f, 0.f};

  for (int s = 0; s < KSq; ++s) {
    int ks = w * KSq + s;
    bf16x8 af[2];
#pragma unroll
    for (int rt = 0; rt < 2; ++rt)
      af[rt] = *reinterpret_cast<const bf16x8*>(Afrag + (((size_t)(mb * 2 + rt) * KS + ks) * 64 + l) * 8);
#pragma unroll
    for (int ct = 0; ct < NCT; ++ct) {
      int tile = (MODE == 2) ? (ct < 4 ? nt : 8 + nt) : nt;
      int cts = ct & 3;
      bf16x8 bf = *reinterpret_cast<const bf16x8*>(Bfrag + (((size_t)(tile * 4 + cts) * KS + ks) * 64 + l) * 8);
#pragma unroll
      for (int rt = 0; rt < 2; ++rt)
        acc[rt][ct] = __builtin_amdgcn_mfma_f32_16x16x32_bf16(af[rt], bf, acc[rt][ct], 0, 0, 0);
    }
  }

#pragma unroll
  for (int rt = 0; rt < 2; ++rt)
#pragma unroll
    for (int ct = 0; ct < NCT; ++ct) red[w][rt][ct][l] = acc[rt][ct];
  __syncthreads();

#pragma unroll
  for (int si = 0; si < 2; ++si) {
    int s = t + si * 256;
    int l2 = s & 63, ct = (s >> 6) & 3, rt = s >> 8;
    f32x4 v = red[0][rt][ct][l2];
#pragma unroll
    for (int ww = 1; ww < 4; ++ww) v += red[ww][rt][ct][l2];
    int col = nt * 64 + ct * 16 + (l2 & 15);
    int row0 = mb * 32 + rt * 16 + (l2 >> 4) * 4;
    if (MODE == 2) {
      f32x4 vh = red[0][rt][ct + 4][l2];
#pragma unroll
      for (int ww = 1; ww < 4; ++ww) vh += red[ww][rt][ct + 4][l2];
      float bz = bias[col], bh = bias[1024 + col];
#pragma unroll
      for (int i = 0; i < 4; ++i) {
        float hv = (1.f - sigmoidf_(v[i] + bz)) * tanhf(vh[i] + bh);
        int row = row0 + i;
        outF[(size_t)row * UNITS_N + col] = hv;
        int k = col;
        outFrag[(((size_t)(row >> 4) * KSo + (k >> 5)) * 64 + (((k >> 3) & 3) * 16 + (row & 15))) * 8 + (k & 7)] = f2bf(hv);
      }
    } else {
      float bv = bias[col];
#pragma unroll
      for (int i = 0; i < 4; ++i) {
        float vv = v[i] + bv;
        int row = row0 + i;
        if (MODE == 0) {
          outF[(size_t)row * N + col] = vv;
        } else {
          int k = col;
          outFrag[(((size_t)(row >> 4) * KSo + (k >> 5)) * 64 + (((k >> 3) & 3) * 16 + (row & 15))) * 8 + (k & 7)] = f2bf(vv);
        }
      }
    }
  }
}

// ==== GEMM1 direct: ZERO barriers / ZERO LDS in the K-loop ====
// BM=64, BN=256 (h halves), grid 512 (2 blocks/CU), 4 waves; wave w owns 64 cols.
// Both MFMA operands loaded per-lane directly in fragment order:
//   A-frag(rt,ks): 8 consecutive f32 at features[mb*64+rt*16+(l&15)][ks*32+(l>>4)*8]
//   B-frag(ct,ks): 16 B at W1s frag offset — W1s is already fragment-ordered.
// Depth-1 register double-buffer (named sets, compile-time indices): loads for
// ks+1 issued before compute of ks; no barrier ever drains them.

#define GD_LOADA(ARR, KF)                                                     \
  { _Pragma("unroll")                                                         \
    for (int rt_ = 0; rt_ < 4; ++rt_) {                                       \
      const float* p_ = Ap + (size_t)rt_ * (16 * FEAT_N) + (size_t)(KF) * 32; \
      ARR[rt_ * 2]     = *reinterpret_cast<const float4*>(p_);                \
      ARR[rt_ * 2 + 1] = *reinterpret_cast<const float4*>(p_ + 4);            \
    } }

#define GD_LOADB(ARR, KF)                                                     \
  { _Pragma("unroll")                                                         \
    for (int ct_ = 0; ct_ < 4; ++ct_)                                         \
      ARR[ct_] = *reinterpret_cast<const bf16x8*>(                            \
          W1s + (((size_t)((KF) * 32 + cb + ct_) * 64) + l) * 8);             \
    }

#define GD_COMPUTE(AARR, BARR)                                                \
  { _Pragma("unroll")                                                         \
    for (int rt_ = 0; rt_ < 4; ++rt_) {                                       \
      union { bf16x8 v; unsigned short s8[8]; } u_;                           \
      float4 x0_ = AARR[rt_ * 2], x1_ = AARR[rt_ * 2 + 1];                    \
      u_.s8[0] = f2bf(x0_.x); u_.s8[1] = f2bf(x0_.y);                         \
      u_.s8[2] = f2bf(x0_.z); u_.s8[3] = f2bf(x0_.w);                         \
      u_.s8[4] = f2bf(x1_.x); u_.s8[5] = f2bf(x1_.y);                         \
      u_.s8[6] = f2bf(x1_.z); u_.s8[7] = f2bf(x1_.w);                         \
      bf16x8 af_ = u_.v;                                                      \
      _Pragma("unroll")                                                       \
      for (int ct_ = 0; ct_ < 4; ++ct_)                                       \
        acc[rt_][ct_] = __builtin_amdgcn_mfma_f32_16x16x32_bf16(              \
            af_, BARR[ct_], acc[rt_][ct_], 0, 0, 0);                          \
    } }

__launch_bounds__(256, 2)
__global__ void k_gemm1d(const float* __restrict__ features,
                         const unsigned short* __restrict__ W1s,
                         const float* __restrict__ hproj,
                         const float* __restrict__ b1,
                         const float* __restrict__ V,
                         float* __restrict__ partials) {
  __shared__ float wlog[4][64];

  int t = threadIdx.x, w = t >> 6, l = t & 63;
  int bid = blockIdx.x;
  int swz = (bid & 7) * 64 + (bid >> 3);   // bijective; h=0/1 of same mb on one XCD
  int h = swz & 1;
  int mb = swz >> 1;

  f32x4 acc[4][4];
#pragma unroll
  for (int rt = 0; rt < 4; ++rt)
#pragma unroll
    for (int ct = 0; ct < 4; ++ct) acc[rt][ct] = (f32x4){0.f, 0.f, 0.f, 0.f};

  const float* Ap = features + (size_t)(mb * 64 + (l & 15)) * FEAT_N + ((l >> 4) * 8);
  const int cb = h * 16 + w * 4;   // 16-col group base within 512

  float4 A0[8], A1[8];
  bf16x8 B0[4], B1[4];

  GD_LOADA(A0, 0);
  GD_LOADB(B0, 0);

  for (int ks = 0; ks < 64; ks += 2) {
    int k1 = ks + 1;
    GD_LOADA(A1, k1);
    GD_LOADB(B1, k1);
    GD_COMPUTE(A0, B0);
    int k2 = (ks + 2 < 64) ? ks + 2 : 63;   // clamped tail (redundant, unused)
    GD_LOADA(A0, k2);
    GD_LOADB(B0, k2);
    GD_COMPUTE(A1, B1);
  }

  // epilogue: partial logits over this half's 256 cols (identical to proven R7)
  float rowpart[16];
#pragma unroll
  for (int i = 0; i < 16; ++i) rowpart[i] = 0.f;
#pragma unroll
  for (int ct = 0; ct < 4; ++ct) {
    int col = h * 256 + w * 64 + ct * 16 + (l & 15);
    float hb = hproj[(size_t)mb * UNITS_N + col] + b1[col];
    float vv = V[col];
#pragma unroll
    for (int rt = 0; rt < 4; ++rt)
#pragma unroll
      for (int i = 0; i < 4; ++i)
        rowpart[rt * 4 + i] += tanhf(acc[rt][ct][i] + hb) * vv;
  }
#pragma unroll
  for (int m = 1; m <= 8; m <<= 1)
#pragma unroll
    for (int i = 0; i < 16; ++i) rowpart[i] += __shfl_xor(rowpart[i], m, 64);
  if ((l & 15) == 0) {
    int g = l >> 4;
#pragma unroll
    for (int rt = 0; rt < 4; ++rt)
#pragma unroll
      for (int i = 0; i < 4; ++i)
        wlog[w][rt * 16 + g * 4 + i] = rowpart[rt * 4 + i];
  }
  __syncthreads();
  if (t < 64) {
    float x = wlog[0][t] + wlog[1][t] + wlog[2][t] + wlog[3][t];
    partials[h * 16384 + mb * 64 + t] = x;
  }
}

// ---- softmax (2 partials) + context + tanh-concat frags; 2 batches per block
__global__ void k_context(const float* __restrict__ features,
                          const float* __restrict__ partials,
                          const float* __restrict__ hidden,
                          unsigned short* __restrict__ tcfrag,
                          float* __restrict__ attn_out) {
  __shared__ float aL[2][64];
  int t = threadIdx.x;           // 0..1023
  int half = t >> 9, tt = t & 511;
  int b = blockIdx.x * 2 + half;
  if (tt < 64) {
    float x = partials[b * 64 + tt] + partials[16384 + b * 64 + tt];
    float mx = x;
#pragma unroll
    for (int m = 1; m < 64; m <<= 1) mx = fmaxf(mx, __shfl_xor(mx, m, 64));
    float e = __expf(x - mx);
    float s = e;
#pragma unroll
    for (int m = 1; m < 64; m <<= 1) s += __shfl_xor(s, m, 64);
    float a = e / s;
    aL[half][tt] = a;
    attn_out[(size_t)b * 64 + tt] = a;
  }
  __syncthreads();
  const float* F = features + (size_t)b * 64 * FEAT_N + tt * 4;
  float a0 = 0.f, a1 = 0.f, a2 = 0.f, a3 = 0.f;
#pragma unroll 4
  for (int lr = 0; lr < 64; ++lr) {
    float4 f = *reinterpret_cast<const float4*>(F + (size_t)lr * FEAT_N);
    float av = aL[half][lr];
    a0 += av * f.x; a1 += av * f.y; a2 += av * f.z; a3 += av * f.w;
  }
  store_frag4(tcfrag, 80, b, tt * 4, tanhf(a0), tanhf(a1), tanhf(a2), tanhf(a3));
  if (tt < 128) {
    const float* H = hidden + (size_t)b * UNITS_N + tt * 4;
    store_frag4(tcfrag, 80, b, 2048 + tt * 4, tanhf(H[0]), tanhf(H[1]), tanhf(H[2]), tanhf(H[3]));
  }
}

// ---- fc2: grid (500, 2)
__launch_bounds__(256)
__global__ void k_fc2(const unsigned short* __restrict__ x1frag,
                      const float* __restrict__ W, const float* __restrict__ bias,
                      float* __restrict__ out) {
  __shared__ unsigned short Bb[4 * 64 * 8];
  int t = threadIdx.x, w = t >> 6, l = t & 63;
  int n0 = blockIdx.x * 64;
  int mh = blockIdx.y;
  f32x4 acc[2][4];
#pragma unroll
  for (int r = 0; r < 2; ++r)
#pragma unroll
    for (int c = 0; c < 4; ++c) acc[r][c] = (f32x4){0.f, 0.f, 0.f, 0.f};

  int sn = t & 63, kc = t >> 6;
  unsigned short* wdst = &Bb[(((sn >> 4) * 64) + ((sn & 15) | (kc << 4))) * 8];
  const float* Wp = W + n0 + sn;
  float wreg[8];
#pragma unroll
  for (int j = 0; j < 8; ++j) wreg[j] = Wp[(size_t)(kc * 8 + j) * VOCAB_N];

  for (int kt = 0; kt < 16; ++kt) {
    __syncthreads();
    {
      union { bf16x8 v; unsigned short s[8]; } p;
#pragma unroll
      for (int j = 0; j < 8; ++j) p.s[j] = f2bf(wreg[j]);
      *reinterpret_cast<bf16x8*>(wdst) = p.v;
    }
    __syncthreads();
    if (kt < 15) {
#pragma unroll
      for (int j = 0; j < 8; ++j) wreg[j] = Wp[(size_t)((kt + 1) * 32 + kc * 8 + j) * VOCAB_N];
    }
    bf16x8 bf[4];
#pragma unroll
    for (int c = 0; c < 4; ++c) bf[c] = *reinterpret_cast<const bf16x8*>(&Bb[((c * 64) + l) * 8]);
#pragma unroll
    for (int rti = 0; rti < 2; ++rti) {
      int rtg = mh * 8 + w * 2 + rti;
      bf16x8 af = *reinterpret_cast<const bf16x8*>(x1frag + ((size_t)(rtg * 16 + kt) * 64 + l) * 8);
#pragma unroll
      for (int c = 0; c < 4; ++c)
        acc[rti][c] = __builtin_amdgcn_mfma_f32_16x16x32_bf16(af, bf[c], acc[rti][c], 0, 0, 0);
    }
  }
#pragma unroll
  for (int c = 0; c < 4; ++c) {
    int col = n0 + c * 16 + (l & 15);
    float bv = bias[col];
#pragma unroll
    for (int rti = 0; rti < 2; ++rti)
#pragma unroll
      for (int i = 0; i < 4; ++i) {
        int row = mh * 128 + w * 32 + rti * 16 + (l >> 4) * 4 + i;
        out[(size_t)row * VOCAB_N + col] = acc[rti][c][i] + bv;
      }
  }
}

extern "C" void kernel_launch(void* const* d_in, const int* in_sizes, int n_in,
                              void* d_out, int out_size, void* d_ws, size_t ws_size,
                              hipStream_t stream) {
  const int*   tok        = (const int*)d_in[0];
  const float* features   = (const float*)d_in[1];
  const float* hidden     = (const float*)d_in[2];
  const float* W1         = (const float*)d_in[3];
  const float* b1         = (const float*)d_in[4];
  const float* W2         = (const float*)d_in[5];
  const float* b2         = (const float*)d_in[6];
  const float* V          = (const float*)d_in[7];
  // d_in[8] = bV: cancels in softmax
  const float* W3         = (const float*)d_in[9];
  const float* b3         = (const float*)d_in[10];
  const float* emb_table  = (const float*)d_in[11];
  const float* gru_kernel = (const float*)d_in[12];
  // d_in[13] = gru_rec: unused (h0 == 0); r-gate columns of gru_kernel also dead
  const float* gru_bias   = (const float*)d_in[14];
  const float* fc1_W      = (const float*)d_in[15];
  const float* fc1_b      = (const float*)d_in[16];
  const float* fc2_W      = (const float*)d_in[17];
  const float* fc2_b      = (const float*)d_in[18];

  float* out_logits = (float*)d_out;
  float* out_h      = out_logits + (size_t)B_N * VOCAB_N;
  float* out_attn   = out_h + (size_t)B_N * UNITS_N;

  char* ws = (char*)d_ws;
  unsigned short* W1s     = (unsigned short*)(ws);               // 2,097,152
  float*          hproj   = (float*)(ws + 2097152);              //   524,288
  unsigned short* hfrag   = (unsigned short*)(ws + 2621440);     //   262,144
  unsigned short* tcfrag  = (unsigned short*)(ws + 2883584);     // 1,310,720
  unsigned short* xinfrag = (unsigned short*)(ws + 4194304);     //   393,216
  unsigned short* hnfrag  = (unsigned short*)(ws + 4587520);     //   262,144
  unsigned short* x1frag  = (unsigned short*)(ws + 4849664);     //   262,144
  unsigned short* W2f     = (unsigned short*)(ws + 5242880);     //   524,288
  unsigned short* W3f     = (unsigned short*)(ws + 5767168);     // 2,621,440
  unsigned short* gruf    = (unsigned short*)(ws + 8388608);     // 1,572,864
  unsigned short* fc1f    = (unsigned short*)(ws + 9961472);     //   524,288
  float*          partials= (float*)(ws + 10485760);             //   131,072

  k_prep_all<<<dim3(1984), dim3(256), 0, stream>>>(W1, W1s, hidden, emb_table, tok,
                                                   hfrag, xinfrag, W2, W2f, W3, W3f,
                                                   gru_kernel, gruf, fc1_W, fc1f);
  // hproj = hidden @ W2 + b2
  k_small2<0><<<dim3(8, 8), dim3(256), 0, stream>>>(hfrag, 16, W2f, b2, hproj, 512,
                                                    (unsigned short*)nullptr, 0);
  // partial logits (barrier-free direct GEMM)
  k_gemm1d<<<dim3(512), dim3(256), 0, stream>>>(features, W1s, hproj, b1, V, partials);
  // softmax + context + tanh-concat frags
  k_context<<<dim3(128), dim3(1024), 0, stream>>>(features, partials, hidden, tcfrag, out_attn);
  // cvh = tc @ W3 + b3 -> xin frags
  k_small2<1><<<dim3(8, 8), dim3(256), 0, stream>>>(tcfrag, 80, W3f, b3, (float*)nullptr, 0,
                                                    xinfrag, 24);
  // gru: z/hh GEMM fused with activation -> out_h + hn frags
  k_small2<2><<<dim3(8, 8), dim3(256), 0, stream>>>(xinfrag, 24, gruf, gru_bias, out_h, 512,
                                                    hnfrag, 16);
  // x1 = h_new @ fc1_W + fc1_b -> frags
  k_small2<1><<<dim3(8, 8), dim3(256), 0, stream>>>(hnfrag, 16, fc1f, fc1_b, (float*)nullptr, 0,
                                                    x1frag, 16);
  // logits_out = x1 @ fc2_W + fc2_b
  k_fc2<<<dim3(500, 2), dim3(256), 0, stream>>>(x1frag, fc2_W, fc2_b, out_logits);
}

// Round 11
// 174.925 us; speedup vs baseline: 1.2936x; 1.2936x over previous
//
#include <hip/hip_runtime.h>
#include <hip/hip_bf16.h>

#define B_N 256
#define L_Q 64
#define FEAT_N 2048
#define UNITS_N 512
#define EMB_N 256
#define VOCAB_N 32000

typedef __attribute__((ext_vector_type(8))) short bf16x8;
typedef __attribute__((ext_vector_type(4))) float f32x4;

__device__ __forceinline__ unsigned short f2bf(float x) {
  union { float f; unsigned int u; } c; c.f = x;
  unsigned int u = c.u + 0x7FFFu + ((c.u >> 16) & 1u);
  return (unsigned short)(u >> 16);
}

__device__ __forceinline__ float sigmoidf_(float x) { return 1.0f / (1.0f + __expf(-x)); }

// A-fragment layout for mfma_f32_16x16x32_bf16 (KS = K/32):
//   ushort index = ((rt*KS + ks)*64 + (lq*16+lr))*8 + j ; row = rt*16+lr, k = ks*32+lq*8+j
__device__ __forceinline__ void store_frag4(unsigned short* base, int KS, int row, int k0,
                                            float a, float b, float c, float d) {
  int rt = row >> 4, lr = row & 15;
  int ks = k0 >> 5, lq = (k0 >> 3) & 3, j0 = k0 & 7;
  union { unsigned long long u; unsigned short s[4]; } p;
  p.s[0] = f2bf(a); p.s[1] = f2bf(b); p.s[2] = f2bf(c); p.s[3] = f2bf(d);
  *reinterpret_cast<unsigned long long*>(base + (((rt * KS + ks) * 64) + (lq * 16 + lr)) * 8 + j0) = p.u;
}

__device__ __forceinline__ void gload_lds16(const void* g, void* lds) {
  __builtin_amdgcn_global_load_lds(
      (const __attribute__((address_space(1))) unsigned int*)(uintptr_t)g,
      (__attribute__((address_space(3))) unsigned int*)(unsigned)(uintptr_t)lds,
      16, 0, 0);
}

// B-fragment weight layout: idx = (((nt*4+ct)*KS + ks)*64 + l)*8 + j
__device__ __forceinline__ void wfrag_one(const float* __restrict__ W, int N, int KS,
                                          unsigned short* __restrict__ dst, int tid, int gruMap) {
  int l = tid & 63;
  int ks = (tid >> 6) % KS;
  int cts = tid / (64 * KS);
  int ct = cts & 3, nt = cts >> 2;
  int nb = gruMap ? (nt < 8 ? nt * 64 : 1024 + (nt - 8) * 64) : nt * 64;
  int ncol = nb + ct * 16 + (l & 15);
  int k0 = ks * 32 + (l >> 4) * 8;
  union { bf16x8 v; unsigned short s[8]; } fr;
#pragma unroll
  for (int j = 0; j < 8; ++j) fr.s[j] = f2bf(W[(size_t)(k0 + j) * N + ncol]);
  *reinterpret_cast<bf16x8*>(dst + (size_t)tid * 8) = fr.v;
}

// ---- fused prep: weights (bb<1984) + features->bf16 frag conversion (bb>=1984)
__global__ void k_prep_all(const float* __restrict__ W1, unsigned short* __restrict__ W1s,
                           const float* __restrict__ hidden,
                           const float* __restrict__ emb_table,
                           const int* __restrict__ tok,
                           unsigned short* __restrict__ hfrag,
                           unsigned short* __restrict__ xinfrag,
                           const float* __restrict__ W2, unsigned short* __restrict__ W2f,
                           const float* __restrict__ W3, unsigned short* __restrict__ W3f,
                           const float* __restrict__ gruK, unsigned short* __restrict__ gruf,
                           const float* __restrict__ fc1W, unsigned short* __restrict__ fc1f,
                           const float* __restrict__ features,
                           unsigned short* __restrict__ ffrag) {
  int bb = blockIdx.x;
  if (bb >= 1984) {
    // ffrag chunk t: l=t&63, rt=(t>>6)&3, ks=(t>>8)&63, mb=t>>14
    // value lane l, j: features[mb*64 + rt*16 + (l&15)][ks*32 + (l>>4)*8 + j]
    int t = (bb - 1984) * 256 + threadIdx.x;
    int l = t & 63, rt = (t >> 6) & 3, ks = (t >> 8) & 63, mb = t >> 14;
    const float* p = features + (size_t)(mb * 64 + rt * 16 + (l & 15)) * FEAT_N
                              + ks * 32 + (l >> 4) * 8;
    float4 x0 = *reinterpret_cast<const float4*>(p);
    float4 x1 = *reinterpret_cast<const float4*>(p + 4);
    union { bf16x8 v; unsigned short s8[8]; } u;
    u.s8[0] = f2bf(x0.x); u.s8[1] = f2bf(x0.y); u.s8[2] = f2bf(x0.z); u.s8[3] = f2bf(x0.w);
    u.s8[4] = f2bf(x1.x); u.s8[5] = f2bf(x1.y); u.s8[6] = f2bf(x1.z); u.s8[7] = f2bf(x1.w);
    *reinterpret_cast<bf16x8*>(ffrag + (size_t)t * 8) = u.v;
    return;
  }
  if (bb < 512) {
    int t = bb * 256 + threadIdx.x;
    int l = t & 63;
    int c = (t >> 6) & 31;
    int kt = t >> 11;
    int n = c * 16 + (l & 15);
    int k0 = kt * 32 + (l >> 4) * 8;
    union { bf16x8 v; unsigned short s[8]; } fr;
#pragma unroll
    for (int j = 0; j < 8; ++j) fr.s[j] = f2bf(W1[(size_t)(k0 + j) * UNITS_N + n]);
    *reinterpret_cast<bf16x8*>(W1s + (size_t)t * 8) = fr.v;
  } else if (bb < 704) {
    int t = (bb - 512) * 256 + threadIdx.x;
    if (t < 32768) {
      int b = t >> 7, k0 = (t & 127) * 4;
      const float* s = hidden + (size_t)b * UNITS_N + k0;
      store_frag4(hfrag, 16, b, k0, s[0], s[1], s[2], s[3]);
    } else if (t < 49152) {
      int t2 = t - 32768;
      int b = t2 >> 6, e0 = (t2 & 63) * 4;
      const float* s = emb_table + (size_t)tok[b] * EMB_N + e0;
      store_frag4(xinfrag, 24, b, 512 + e0, s[0], s[1], s[2], s[3]);
    }
  } else if (bb < 832) {
    wfrag_one(W2, 512, 16, W2f, (bb - 704) * 256 + threadIdx.x, 0);
  } else if (bb < 1472) {
    wfrag_one(W3, 512, 80, W3f, (bb - 832) * 256 + threadIdx.x, 0);
  } else if (bb < 1856) {
    wfrag_one(gruK, 1536, 24, gruf, (bb - 1472) * 256 + threadIdx.x, 1);
  } else {
    wfrag_one(fc1W, 512, 16, fc1f, (bb - 1856) * 256 + threadIdx.x, 0);
  }
}

// ---- split-K small GEMM (unchanged, proven)
template <int MODE>
__launch_bounds__(256)
__global__ void k_small2(const unsigned short* __restrict__ Afrag, int KS,
                         const unsigned short* __restrict__ Bfrag,
                         const float* __restrict__ bias,
                         float* __restrict__ outF, int N,
                         unsigned short* __restrict__ outFrag, int KSo) {
  constexpr int NCT = (MODE == 2) ? 8 : 4;
  __shared__ f32x4 red[4][2][NCT][64];
  int t = threadIdx.x, w = t >> 6, l = t & 63;
  int nt = blockIdx.x;
  int mb = blockIdx.y;
  int KSq = KS >> 2;

  f32x4 acc[2][NCT];
#pragma unroll
  for (int rt = 0; rt < 2; ++rt)
#pragma unroll
    for (int ct = 0; ct < NCT; ++ct) acc[rt][ct] = (f32x4){0.f, 0.f, 0.f, 0.f};

  for (int s = 0; s < KSq; ++s) {
    int ks = w * KSq + s;
    bf16x8 af[2];
#pragma unroll
    for (int rt = 0; rt < 2; ++rt)
      af[rt] = *reinterpret_cast<const bf16x8*>(Afrag + (((size_t)(mb * 2 + rt) * KS + ks) * 64 + l) * 8);
#pragma unroll
    for (int ct = 0; ct < NCT; ++ct) {
      int tile = (MODE == 2) ? (ct < 4 ? nt : 8 + nt) : nt;
      int cts = ct & 3;
      bf16x8 bf = *reinterpret_cast<const bf16x8*>(Bfrag + (((size_t)(tile * 4 + cts) * KS + ks) * 64 + l) * 8);
#pragma unroll
      for (int rt = 0; rt < 2; ++rt)
        acc[rt][ct] = __builtin_amdgcn_mfma_f32_16x16x32_bf16(af[rt], bf, acc[rt][ct], 0, 0, 0);
    }
  }

#pragma unroll
  for (int rt = 0; rt < 2; ++rt)
#pragma unroll
    for (int ct = 0; ct < NCT; ++ct) red[w][rt][ct][l] = acc[rt][ct];
  __syncthreads();

#pragma unroll
  for (int si = 0; si < 2; ++si) {
    int s = t + si * 256;
    int l2 = s & 63, ct = (s >> 6) & 3, rt = s >> 8;
    f32x4 v = red[0][rt][ct][l2];
#pragma unroll
    for (int ww = 1; ww < 4; ++ww) v += red[ww][rt][ct][l2];
    int col = nt * 64 + ct * 16 + (l2 & 15);
    int row0 = mb * 32 + rt * 16 + (l2 >> 4) * 4;
    if (MODE == 2) {
      f32x4 vh = red[0][rt][ct + 4][l2];
#pragma unroll
      for (int ww = 1; ww < 4; ++ww) vh += red[ww][rt][ct + 4][l2];
      float bz = bias[col], bh = bias[1024 + col];
#pragma unroll
      for (int i = 0; i < 4; ++i) {
        float hv = (1.f - sigmoidf_(v[i] + bz)) * tanhf(vh[i] + bh);
        int row = row0 + i;
        outF[(size_t)row * UNITS_N + col] = hv;
        int k = col;
        outFrag[(((size_t)(row >> 4) * KSo + (k >> 5)) * 64 + (((k >> 3) & 3) * 16 + (row & 15))) * 8 + (k & 7)] = f2bf(hv);
      }
    } else {
      float bv = bias[col];
#pragma unroll
      for (int i = 0; i < 4; ++i) {
        float vv = v[i] + bv;
        int row = row0 + i;
        if (MODE == 0) {
          outF[(size_t)row * N + col] = vv;
        } else {
          int k = col;
          outFrag[(((size_t)(row >> 4) * KSo + (k >> 5)) * 64 + (((k >> 3) & 3) * 16 + (row & 15))) * 8 + (k & 7)] = f2bf(vv);
        }
      }
    }
  }
}

// ==== GEMM1 (fast path): pure global_load_lds pipeline, zero VGPR loads in loop ====
// BM=64, BN=128, BK=64, *** 32 K-steps (K=2048) ***, grid 1024, 4 waves.
// Per step: stage A(8KB) + B(16KB) for kt+1 via gload_lds, 16 MFMA/wave from buf kt,
// ONE __syncthreads. No f32->bf16 in loop. (R10 bug: loop ran 16 steps = half of K.)
#define GF_STAGE(KT, BUF)                                                          \
  { _Pragma("unroll")                                                              \
    for (int i_ = 0; i_ < 2; ++i_) {                                               \
      int g_ = w * 2 + i_;                                                         \
      gload_lds16(FfC + (((size_t)(mb * 16384 + (KT) * 512 + g_ * 64 + l)) << 4),  \
                  AbC + (size_t)(BUF) * 8192 + (g_ << 10));                        \
    }                                                                              \
    _Pragma("unroll")                                                              \
    for (int j_ = 0; j_ < 4; ++j_) {                                               \
      int u_ = w * 4 + j_;                                                         \
      size_t ch_ = (size_t)((2 * (KT) + (u_ >> 3)) * 32 + nq * 8 + (u_ & 7));      \
      gload_lds16(W1c + (((ch_ * 64) + l) << 4),                                   \
                  BbC + (size_t)(BUF) * 16384 + (u_ << 10));                       \
    } }

__launch_bounds__(256, 3)
__global__ void k_gemm1f(const unsigned short* __restrict__ ffrag,
                         const unsigned short* __restrict__ W1s,
                         const float* __restrict__ hproj,
                         const float* __restrict__ b1,
                         const float* __restrict__ V,
                         float* __restrict__ partials) {
  __shared__ unsigned short Ab[2][4096];   // 2 x 8 KB  [ks2][rt][l][8]
  __shared__ unsigned short Bb[2][8192];   // 2 x 16 KB [ks2][c][l][8]
  __shared__ float wlog[4][64];

  int t = threadIdx.x, w = t >> 6, l = t & 63;
  int bid = blockIdx.x;
  int swz = (bid & 7) * 128 + (bid >> 3);  // bijective, 1024 = 8*128; mb-major per XCD
  int nq = swz & 3;
  int mb = swz >> 2;

  f32x4 acc[4][2];
#pragma unroll
  for (int rt = 0; rt < 4; ++rt)
#pragma unroll
    for (int ct = 0; ct < 2; ++ct) acc[rt][ct] = (f32x4){0.f, 0.f, 0.f, 0.f};

  const char* FfC = (const char*)ffrag;
  const char* W1c = (const char*)W1s;
  char* AbC = (char*)Ab;
  char* BbC = (char*)Bb;

  GF_STAGE(0, 0);
  __syncthreads();

  for (int kt = 0; kt < 32; ++kt) {          // K = 32 steps x BK=64 = 2048
    int buf = kt & 1;
    if (kt + 1 < 32) GF_STAGE(kt + 1, buf ^ 1);
#pragma unroll
    for (int ks2 = 0; ks2 < 2; ++ks2) {
      bf16x8 af[4];
#pragma unroll
      for (int rt = 0; rt < 4; ++rt)
        af[rt] = *reinterpret_cast<const bf16x8*>(&Ab[buf][((ks2 * 4 + rt) * 64 + l) * 8]);
#pragma unroll
      for (int ct = 0; ct < 2; ++ct) {
        bf16x8 bfr = *reinterpret_cast<const bf16x8*>(&Bb[buf][((ks2 * 8 + w * 2 + ct) * 64 + l) * 8]);
#pragma unroll
        for (int rt = 0; rt < 4; ++rt)
          acc[rt][ct] = __builtin_amdgcn_mfma_f32_16x16x32_bf16(af[rt], bfr, acc[rt][ct], 0, 0, 0);
      }
    }
    __syncthreads();
  }

  // epilogue: partial logits over this quarter's 128 cols
  float rowpart[16];
#pragma unroll
  for (int i = 0; i < 16; ++i) rowpart[i] = 0.f;
#pragma unroll
  for (int ct = 0; ct < 2; ++ct) {
    int col = nq * 128 + (w * 2 + ct) * 16 + (l & 15);
    float hb = hproj[(size_t)mb * UNITS_N + col] + b1[col];
    float vv = V[col];
#pragma unroll
    for (int rt = 0; rt < 4; ++rt)
#pragma unroll
      for (int i = 0; i < 4; ++i)
        rowpart[rt * 4 + i] += tanhf(acc[rt][ct][i] + hb) * vv;
  }
#pragma unroll
  for (int m = 1; m <= 8; m <<= 1)
#pragma unroll
    for (int i = 0; i < 16; ++i) rowpart[i] += __shfl_xor(rowpart[i], m, 64);
  if ((l & 15) == 0) {
    int g = l >> 4;
#pragma unroll
    for (int rt = 0; rt < 4; ++rt)
#pragma unroll
      for (int i = 0; i < 4; ++i)
        wlog[w][rt * 16 + g * 4 + i] = rowpart[rt * 4 + i];
  }
  __syncthreads();
  if (t < 64) {
    float x = wlog[0][t] + wlog[1][t] + wlog[2][t] + wlog[3][t];
    partials[nq * 16384 + mb * 64 + t] = x;
  }
}

// ==== GEMM1 (fallback, proven R7): 2-phase register pipeline ====
#define G7_LOADA(S0, S1, KF)                                       \
  { const float* p_ = Ap + (size_t)(KF) * 32;                      \
    S0 = *reinterpret_cast<const float4*>(p_);                     \
    S1 = *reinterpret_cast<const float4*>(p_ + 4); }

#define G7_STAGEB(KF, BUF)                                                          \
  { _Pragma("unroll")                                                               \
    for (int i_ = 0; i_ < 4; ++i_) {                                                \
      int s_ = w * 4 + i_;                                                          \
      gload_lds16(W1c + ((size_t)((KF) * 32 + h * 16 + s_) << 10) + (size_t)l * 16, \
                  BbC + (size_t)(BUF) * 16384 + (s_ << 10));                        \
    } }

#define G7_CONVA(S0, S1, BUF)                                      \
  { union { bf16x8 v; unsigned short s8[8]; } u_;                  \
    u_.s8[0] = f2bf(S0.x); u_.s8[1] = f2bf(S0.y);                  \
    u_.s8[2] = f2bf(S0.z); u_.s8[3] = f2bf(S0.w);                  \
    u_.s8[4] = f2bf(S1.x); u_.s8[5] = f2bf(S1.y);                  \
    u_.s8[6] = f2bf(S1.z); u_.s8[7] = f2bf(S1.w);                  \
    *reinterpret_cast<bf16x8*>(&Ab[BUF][awi]) = u_.v; }

#define G7_BODY(KT, L0, L1, C0, C1)                                           \
  { const int kt_ = (KT);                                                     \
    if (kt_ + 2 < 64) G7_LOADA(L0, L1, kt_ + 2);                              \
    if (kt_ + 1 < 64) {                                                       \
      G7_STAGEB(kt_ + 1, (kt_ + 1) & 1);                                      \
      G7_CONVA(C0, C1, (kt_ + 1) & 1);                                        \
    }                                                                         \
    bf16x8 af_[4];                                                            \
    _Pragma("unroll")                                                         \
    for (int rt_ = 0; rt_ < 4; ++rt_)                                         \
      af_[rt_] = *reinterpret_cast<const bf16x8*>(                            \
          &Ab[kt_ & 1][((rt_ * 4 + (l >> 4)) * 16 + (l & 15)) * 8]);          \
    _Pragma("unroll")                                                         \
    for (int ct_ = 0; ct_ < 4; ++ct_) {                                       \
      bf16x8 bfr_ = *reinterpret_cast<const bf16x8*>(                         \
          &Bb[kt_ & 1][((w * 4 + ct_) * 64 + l) * 8]);                        \
      _Pragma("unroll")                                                       \
      for (int rt_ = 0; rt_ < 4; ++rt_)                                       \
        acc[rt_][ct_] = __builtin_amdgcn_mfma_f32_16x16x32_bf16(              \
            af_[rt_], bfr_, acc[rt_][ct_], 0, 0, 0);                          \
    }                                                                         \
    __syncthreads();                                                          \
  }

__launch_bounds__(256, 2)
__global__ void k_gemm1p(const float* __restrict__ features,
                         const unsigned short* __restrict__ W1s,
                         const float* __restrict__ hproj,
                         const float* __restrict__ b1,
                         const float* __restrict__ V,
                         float* __restrict__ partials) {
  __shared__ unsigned short Bb[2][8192];
  __shared__ unsigned short Ab[2][2048];
  __shared__ float wlog[4][64];

  int t = threadIdx.x, w = t >> 6, l = t & 63;
  int bid = blockIdx.x;
  int swz = (bid & 7) * 64 + (bid >> 3);
  int h = swz & 1;
  int mb = swz >> 1;

  f32x4 acc[4][4];
#pragma unroll
  for (int rt = 0; rt < 4; ++rt)
#pragma unroll
    for (int ct = 0; ct < 4; ++ct) acc[rt][ct] = (f32x4){0.f, 0.f, 0.f, 0.f};

  int r = t >> 2, q = t & 3;
  const float* Ap = features + (size_t)(mb * 64 + r) * FEAT_N + q * 8;
  const int awi = (((r >> 4) * 4 + q) * 16 + (r & 15)) * 8;
  const char* W1c = (const char*)W1s;
  char* BbC = (char*)Bb;

  float4 a00, a01, a10, a11;
  G7_LOADA(a00, a01, 0);
  G7_LOADA(a10, a11, 1);
  G7_STAGEB(0, 0);
  G7_CONVA(a00, a01, 0);
  __syncthreads();

  for (int kt2 = 0; kt2 < 64; kt2 += 2) {
    G7_BODY(kt2,     a00, a01, a10, a11);
    G7_BODY(kt2 + 1, a10, a11, a00, a01);
  }

  float rowpart[16];
#pragma unroll
  for (int i = 0; i < 16; ++i) rowpart[i] = 0.f;
#pragma unroll
  for (int ct = 0; ct < 4; ++ct) {
    int col = h * 256 + w * 64 + ct * 16 + (l & 15);
    float hb = hproj[(size_t)mb * UNITS_N + col] + b1[col];
    float vv = V[col];
#pragma unroll
    for (int rt = 0; rt < 4; ++rt)
#pragma unroll
      for (int i = 0; i < 4; ++i)
        rowpart[rt * 4 + i] += tanhf(acc[rt][ct][i] + hb) * vv;
  }
#pragma unroll
  for (int m = 1; m <= 8; m <<= 1)
#pragma unroll
    for (int i = 0; i < 16; ++i) rowpart[i] += __shfl_xor(rowpart[i], m, 64);
  if ((l & 15) == 0) {
    int g = l >> 4;
#pragma unroll
    for (int rt = 0; rt < 4; ++rt)
#pragma unroll
      for (int i = 0; i < 4; ++i)
        wlog[w][rt * 16 + g * 4 + i] = rowpart[rt * 4 + i];
  }
  __syncthreads();
  if (t < 64) {
    float x = wlog[0][t] + wlog[1][t] + wlog[2][t] + wlog[3][t];
    partials[h * 16384 + mb * 64 + t] = x;
  }
}

// ---- softmax (nsets partials) + context + tanh-concat frags; 2 batches per block
__global__ void k_context(const float* __restrict__ features,
                          const float* __restrict__ partials,
                          const float* __restrict__ hidden,
                          unsigned short* __restrict__ tcfrag,
                          float* __restrict__ attn_out, int nsets) {
  __shared__ float aL[2][64];
  int t = threadIdx.x;           // 0..1023
  int half = t >> 9, tt = t & 511;
  int b = blockIdx.x * 2 + half;
  if (tt < 64) {
    float x = 0.f;
    for (int p = 0; p < nsets; ++p) x += partials[p * 16384 + b * 64 + tt];
    float mx = x;
#pragma unroll
    for (int m = 1; m < 64; m <<= 1) mx = fmaxf(mx, __shfl_xor(mx, m, 64));
    float e = __expf(x - mx);
    float s = e;
#pragma unroll
    for (int m = 1; m < 64; m <<= 1) s += __shfl_xor(s, m, 64);
    float a = e / s;
    aL[half][tt] = a;
    attn_out[(size_t)b * 64 + tt] = a;
  }
  __syncthreads();
  const float* F = features + (size_t)b * 64 * FEAT_N + tt * 4;
  float a0 = 0.f, a1 = 0.f, a2 = 0.f, a3 = 0.f;
#pragma unroll 4
  for (int lr = 0; lr < 64; ++lr) {
    float4 f = *reinterpret_cast<const float4*>(F + (size_t)lr * FEAT_N);
    float av = aL[half][lr];
    a0 += av * f.x; a1 += av * f.y; a2 += av * f.z; a3 += av * f.w;
  }
  store_frag4(tcfrag, 80, b, tt * 4, tanhf(a0), tanhf(a1), tanhf(a2), tanhf(a3));
  if (tt < 128) {
    const float* H = hidden + (size_t)b * UNITS_N + tt * 4;
    store_frag4(tcfrag, 80, b, 2048 + tt * 4, tanhf(H[0]), tanhf(H[1]), tanhf(H[2]), tanhf(H[3]));
  }
}

// ---- fc2: grid (500, 2)
__launch_bounds__(256)
__global__ void k_fc2(const unsigned short* __restrict__ x1frag,
                      const float* __restrict__ W, const float* __restrict__ bias,
                      float* __restrict__ out) {
  __shared__ unsigned short Bb[4 * 64 * 8];
  int t = threadIdx.x, w = t >> 6, l = t & 63;
  int n0 = blockIdx.x * 64;
  int mh = blockIdx.y;
  f32x4 acc[2][4];
#pragma unroll
  for (int r = 0; r < 2; ++r)
#pragma unroll
    for (int c = 0; c < 4; ++c) acc[r][c] = (f32x4){0.f, 0.f, 0.f, 0.f};

  int sn = t & 63, kc = t >> 6;
  unsigned short* wdst = &Bb[(((sn >> 4) * 64) + ((sn & 15) | (kc << 4))) * 8];
  const float* Wp = W + n0 + sn;
  float wreg[8];
#pragma unroll
  for (int j = 0; j < 8; ++j) wreg[j] = Wp[(size_t)(kc * 8 + j) * VOCAB_N];

  for (int kt = 0; kt < 16; ++kt) {
    __syncthreads();
    {
      union { bf16x8 v; unsigned short s[8]; } p;
#pragma unroll
      for (int j = 0; j < 8; ++j) p.s[j] = f2bf(wreg[j]);
      *reinterpret_cast<bf16x8*>(wdst) = p.v;
    }
    __syncthreads();
    if (kt < 15) {
#pragma unroll
      for (int j = 0; j < 8; ++j) wreg[j] = Wp[(size_t)((kt + 1) * 32 + kc * 8 + j) * VOCAB_N];
    }
    bf16x8 bf[4];
#pragma unroll
    for (int c = 0; c < 4; ++c) bf[c] = *reinterpret_cast<const bf16x8*>(&Bb[((c * 64) + l) * 8]);
#pragma unroll
    for (int rti = 0; rti < 2; ++rti) {
      int rtg = mh * 8 + w * 2 + rti;
      bf16x8 af = *reinterpret_cast<const bf16x8*>(x1frag + ((size_t)(rtg * 16 + kt) * 64 + l) * 8);
#pragma unroll
      for (int c = 0; c < 4; ++c)
        acc[rti][c] = __builtin_amdgcn_mfma_f32_16x16x32_bf16(af, bf[c], acc[rti][c], 0, 0, 0);
    }
  }
#pragma unroll
  for (int c = 0; c < 4; ++c) {
    int col = n0 + c * 16 + (l & 15);
    float bv = bias[col];
#pragma unroll
    for (int rti = 0; rti < 2; ++rti)
#pragma unroll
      for (int i = 0; i < 4; ++i) {
        int row = mh * 128 + w * 32 + rti * 16 + (l >> 4) * 4 + i;
        out[(size_t)row * VOCAB_N + col] = acc[rti][c][i] + bv;
      }
  }
}

extern "C" void kernel_launch(void* const* d_in, const int* in_sizes, int n_in,
                              void* d_out, int out_size, void* d_ws, size_t ws_size,
                              hipStream_t stream) {
  const int*   tok        = (const int*)d_in[0];
  const float* features   = (const float*)d_in[1];
  const float* hidden     = (const float*)d_in[2];
  const float* W1         = (const float*)d_in[3];
  const float* b1         = (const float*)d_in[4];
  const float* W2         = (const float*)d_in[5];
  const float* b2         = (const float*)d_in[6];
  const float* V          = (const float*)d_in[7];
  // d_in[8] = bV: cancels in softmax
  const float* W3         = (const float*)d_in[9];
  const float* b3         = (const float*)d_in[10];
  const float* emb_table  = (const float*)d_in[11];
  const float* gru_kernel = (const float*)d_in[12];
  // d_in[13] = gru_rec: unused (h0 == 0); r-gate columns of gru_kernel also dead
  const float* gru_bias   = (const float*)d_in[14];
  const float* fc1_W      = (const float*)d_in[15];
  const float* fc1_b      = (const float*)d_in[16];
  const float* fc2_W      = (const float*)d_in[17];
  const float* fc2_b      = (const float*)d_in[18];

  float* out_logits = (float*)d_out;
  float* out_h      = out_logits + (size_t)B_N * VOCAB_N;
  float* out_attn   = out_h + (size_t)B_N * UNITS_N;

  char* ws = (char*)d_ws;
  unsigned short* W1s     = (unsigned short*)(ws);               // 2,097,152
  float*          hproj   = (float*)(ws + 2097152);              //   524,288
  unsigned short* hfrag   = (unsigned short*)(ws + 2621440);     //   262,144
  unsigned short* tcfrag  = (unsigned short*)(ws + 2883584);     // 1,310,720
  unsigned short* xinfrag = (unsigned short*)(ws + 4194304);     //   393,216
  unsigned short* hnfrag  = (unsigned short*)(ws + 4587520);     //   262,144
  unsigned short* x1frag  = (unsigned short*)(ws + 4849664);     //   262,144
  unsigned short* W2f     = (unsigned short*)(ws + 5242880);     //   524,288
  unsigned short* W3f     = (unsigned short*)(ws + 5767168);     // 2,621,440
  unsigned short* gruf    = (unsigned short*)(ws + 8388608);     // 1,572,864
  unsigned short* fc1f    = (unsigned short*)(ws + 9961472);     //   524,288
  float*          partials= (float*)(ws + 10485760);             //   262,144 (4 sets)
  unsigned short* ffrag   = (unsigned short*)(ws + 10747904);    // 67,108,864

  const size_t WS_NEED = 10747904ull + 67108864ull;   // 77,856,768
  const bool fast = (ws_size >= WS_NEED);

  k_prep_all<<<dim3(fast ? 18368 : 1984), dim3(256), 0, stream>>>(
      W1, W1s, hidden, emb_table, tok, hfrag, xinfrag, W2, W2f, W3, W3f,
      gru_kernel, gruf, fc1_W, fc1f, features, ffrag);
  // hproj = hidden @ W2 + b2
  k_small2<0><<<dim3(8, 8), dim3(256), 0, stream>>>(hfrag, 16, W2f, b2, hproj, 512,
                                                    (unsigned short*)nullptr, 0);
  // partial logits
  if (fast)
    k_gemm1f<<<dim3(1024), dim3(256), 0, stream>>>(ffrag, W1s, hproj, b1, V, partials);
  else
    k_gemm1p<<<dim3(512), dim3(256), 0, stream>>>(features, W1s, hproj, b1, V, partials);
  // softmax + context + tanh-concat frags
  k_context<<<dim3(128), dim3(1024), 0, stream>>>(features, partials, hidden, tcfrag,
                                                  out_attn, fast ? 4 : 2);
  // cvh = tc @ W3 + b3 -> xin frags
  k_small2<1><<<dim3(8, 8), dim3(256), 0, stream>>>(tcfrag, 80, W3f, b3, (float*)nullptr, 0,
                                                    xinfrag, 24);
  // gru: z/hh GEMM fused with activation -> out_h + hn frags
  k_small2<2><<<dim3(8, 8), dim3(256), 0, stream>>>(xinfrag, 24, gruf, gru_bias, out_h, 512,
                                                    hnfrag, 16);
  // x1 = h_new @ fc1_W + fc1_b -> frags
  k_small2<1><<<dim3(8, 8), dim3(256), 0, stream>>>(hnfrag, 16, fc1f, fc1_b, (float*)nullptr, 0,
                                                    x1frag, 16);
  // logits_out = x1 @ fc2_W + fc2_b
  k_fc2<<<dim3(500, 2), dim3(256), 0, stream>>>(x1frag, fc2_W, fc2_b, out_logits);
}

// Round 13
// 156.412 us; speedup vs baseline: 1.4467x; 1.1184x over previous
//
#include <hip/hip_runtime.h>
#include <hip/hip_bf16.h>

#define B_N 256
#define L_Q 64
#define FEAT_N 2048
#define UNITS_N 512
#define EMB_N 256
#define VOCAB_N 32000

typedef __attribute__((ext_vector_type(8))) short bf16x8;
typedef __attribute__((ext_vector_type(4))) float f32x4;

__device__ __forceinline__ unsigned short f2bf(float x) {
  union { float f; unsigned int u; } c; c.f = x;
  unsigned int u = c.u + 0x7FFFu + ((c.u >> 16) & 1u);
  return (unsigned short)(u >> 16);
}

// pack two f32 -> u32 holding 2 bf16 (round-half-up; 2 VALU ops/value)
__device__ __forceinline__ unsigned int pack2bf(float a, float b) {
  union { float f; unsigned int u; } x, y; x.f = a; y.f = b;
  return ((y.u + 0x8000u) & 0xFFFF0000u) | ((x.u + 0x8000u) >> 16);
}

__device__ __forceinline__ float sigmoidf_(float x) { return 1.0f / (1.0f + __expf(-x)); }

// A-fragment layout for mfma_f32_16x16x32_bf16 (KS = K/32):
//   ushort index = ((rt*KS + ks)*64 + (lq*16+lr))*8 + j ; row = rt*16+lr, k = ks*32+lq*8+j
__device__ __forceinline__ void store_frag4(unsigned short* base, int KS, int row, int k0,
                                            float a, float b, float c, float d) {
  int rt = row >> 4, lr = row & 15;
  int ks = k0 >> 5, lq = (k0 >> 3) & 3, j0 = k0 & 7;
  union { unsigned long long u; unsigned short s[4]; } p;
  p.s[0] = f2bf(a); p.s[1] = f2bf(b); p.s[2] = f2bf(c); p.s[3] = f2bf(d);
  *reinterpret_cast<unsigned long long*>(base + (((rt * KS + ks) * 64) + (lq * 16 + lr)) * 8 + j0) = p.u;
}

__device__ __forceinline__ void gload_lds16(const void* g, void* lds) {
  __builtin_amdgcn_global_load_lds(
      (const __attribute__((address_space(1))) unsigned int*)(uintptr_t)g,
      (__attribute__((address_space(3))) unsigned int*)(unsigned)(uintptr_t)lds,
      16, 0, 0);
}

// B-fragment weight layout: idx = (((nt*4+ct)*KS + ks)*64 + l)*8 + j
__device__ __forceinline__ void wfrag_one(const float* __restrict__ W, int N, int KS,
                                          unsigned short* __restrict__ dst, int tid, int gruMap) {
  int l = tid & 63;
  int ks = (tid >> 6) % KS;
  int cts = tid / (64 * KS);
  int ct = cts & 3, nt = cts >> 2;
  int nb = gruMap ? (nt < 8 ? nt * 64 : 1024 + (nt - 8) * 64) : nt * 64;
  int ncol = nb + ct * 16 + (l & 15);
  int k0 = ks * 32 + (l >> 4) * 8;
  union { bf16x8 v; unsigned short s[8]; } fr;
#pragma unroll
  for (int j = 0; j < 8; ++j) fr.s[j] = f2bf(W[(size_t)(k0 + j) * N + ncol]);
  *reinterpret_cast<bf16x8*>(dst + (size_t)tid * 8) = fr.v;
}

// ---- fused prep
__global__ void k_prep_all(const float* __restrict__ W1, unsigned short* __restrict__ W1s,
                           const float* __restrict__ hidden,
                           const float* __restrict__ emb_table,
                           const int* __restrict__ tok,
                           unsigned short* __restrict__ hfrag,
                           unsigned short* __restrict__ xinfrag,
                           const float* __restrict__ W2, unsigned short* __restrict__ W2f,
                           const float* __restrict__ W3, unsigned short* __restrict__ W3f,
                           const float* __restrict__ gruK, unsigned short* __restrict__ gruf,
                           const float* __restrict__ fc1W, unsigned short* __restrict__ fc1f) {
  int bb = blockIdx.x;
  if (bb < 512) {
    int t = bb * 256 + threadIdx.x;
    int l = t & 63;
    int c = (t >> 6) & 31;
    int kt = t >> 11;
    int n = c * 16 + (l & 15);
    int k0 = kt * 32 + (l >> 4) * 8;
    union { bf16x8 v; unsigned short s[8]; } fr;
#pragma unroll
    for (int j = 0; j < 8; ++j) fr.s[j] = f2bf(W1[(size_t)(k0 + j) * UNITS_N + n]);
    *reinterpret_cast<bf16x8*>(W1s + (size_t)t * 8) = fr.v;
  } else if (bb < 704) {
    int t = (bb - 512) * 256 + threadIdx.x;
    if (t < 32768) {
      int b = t >> 7, k0 = (t & 127) * 4;
      const float* s = hidden + (size_t)b * UNITS_N + k0;
      store_frag4(hfrag, 16, b, k0, s[0], s[1], s[2], s[3]);
    } else if (t < 49152) {
      int t2 = t - 32768;
      int b = t2 >> 6, e0 = (t2 & 63) * 4;
      const float* s = emb_table + (size_t)tok[b] * EMB_N + e0;
      store_frag4(xinfrag, 24, b, 512 + e0, s[0], s[1], s[2], s[3]);
    }
  } else if (bb < 832) {
    wfrag_one(W2, 512, 16, W2f, (bb - 704) * 256 + threadIdx.x, 0);
  } else if (bb < 1472) {
    wfrag_one(W3, 512, 80, W3f, (bb - 832) * 256 + threadIdx.x, 0);
  } else if (bb < 1856) {
    wfrag_one(gruK, 1536, 24, gruf, (bb - 1472) * 256 + threadIdx.x, 1);
  } else {
    wfrag_one(fc1W, 512, 16, fc1f, (bb - 1856) * 256 + threadIdx.x, 0);
  }
}

// ---- split-K small GEMM (unchanged, proven)
template <int MODE>
__launch_bounds__(256)
__global__ void k_small2(const unsigned short* __restrict__ Afrag, int KS,
                         const unsigned short* __restrict__ Bfrag,
                         const float* __restrict__ bias,
                         float* __restrict__ outF, int N,
                         unsigned short* __restrict__ outFrag, int KSo) {
  constexpr int NCT = (MODE == 2) ? 8 : 4;
  __shared__ f32x4 red[4][2][NCT][64];
  int t = threadIdx.x, w = t >> 6, l = t & 63;
  int nt = blockIdx.x;
  int mb = blockIdx.y;
  int KSq = KS >> 2;

  f32x4 acc[2][NCT];
#pragma unroll
  for (int rt = 0; rt < 2; ++rt)
#pragma unroll
    for (int ct = 0; ct < NCT; ++ct) acc[rt][ct] = (f32x4){0.f, 0.f, 0.f, 0.f};

  for (int s = 0; s < KSq; ++s) {
    int ks = w * KSq + s;
    bf16x8 af[2];
#pragma unroll
    for (int rt = 0; rt < 2; ++rt)
      af[rt] = *reinterpret_cast<const bf16x8*>(Afrag + (((size_t)(mb * 2 + rt) * KS + ks) * 64 + l) * 8);
#pragma unroll
    for (int ct = 0; ct < NCT; ++ct) {
      int tile = (MODE == 2) ? (ct < 4 ? nt : 8 + nt) : nt;
      int cts = ct & 3;
      bf16x8 bf = *reinterpret_cast<const bf16x8*>(Bfrag + (((size_t)(tile * 4 + cts) * KS + ks) * 64 + l) * 8);
#pragma unroll
      for (int rt = 0; rt < 2; ++rt)
        acc[rt][ct] = __builtin_amdgcn_mfma_f32_16x16x32_bf16(af[rt], bf, acc[rt][ct], 0, 0, 0);
    }
  }

#pragma unroll
  for (int rt = 0; rt < 2; ++rt)
#pragma unroll
    for (int ct = 0; ct < NCT; ++ct) red[w][rt][ct][l] = acc[rt][ct];
  __syncthreads();

#pragma unroll
  for (int si = 0; si < 2; ++si) {
    int s = t + si * 256;
    int l2 = s & 63, ct = (s >> 6) & 3, rt = s >> 8;
    f32x4 v = red[0][rt][ct][l2];
#pragma unroll
    for (int ww = 1; ww < 4; ++ww) v += red[ww][rt][ct][l2];
    int col = nt * 64 + ct * 16 + (l2 & 15);
    int row0 = mb * 32 + rt * 16 + (l2 >> 4) * 4;
    if (MODE == 2) {
      f32x4 vh = red[0][rt][ct + 4][l2];
#pragma unroll
      for (int ww = 1; ww < 4; ++ww) vh += red[ww][rt][ct + 4][l2];
      float bz = bias[col], bh = bias[1024 + col];
#pragma unroll
      for (int i = 0; i < 4; ++i) {
        float hv = (1.f - sigmoidf_(v[i] + bz)) * tanhf(vh[i] + bh);
        int row = row0 + i;
        outF[(size_t)row * UNITS_N + col] = hv;
        int k = col;
        outFrag[(((size_t)(row >> 4) * KSo + (k >> 5)) * 64 + (((k >> 3) & 3) * 16 + (row & 15))) * 8 + (k & 7)] = f2bf(hv);
      }
    } else {
      float bv = bias[col];
#pragma unroll
      for (int i = 0; i < 4; ++i) {
        float vv = v[i] + bv;
        int row = row0 + i;
        if (MODE == 0) {
          outF[(size_t)row * N + col] = vv;
        } else {
          int k = col;
          outFrag[(((size_t)(row >> 4) * KSo + (k >> 5)) * 64 + (((k >> 3) & 3) * 16 + (row & 15))) * 8 + (k & 7)] = f2bf(vv);
        }
      }
    }
  }
}

// ==== GEMM1q: BM=128, BN=128, BK=64, 32 fat steps, stage-early B + depth-2 A regs ====
// grid 512 (2 blocks/CU, 64.5 KB LDS), 4 waves; wave w = rows [w*32,w*32+32) x all 128 cols
// -> 32 MFMA/wave/step. Registers held in float4 arrays with LITERAL indices only.

#define GQ_LOADA(S, KF)                                            \
  { const float* p0_ = Ap0 + (size_t)(KF) * 64;                    \
    const float* p1_ = Ap1 + (size_t)(KF) * 64;                    \
    S[0] = *reinterpret_cast<const float4*>(p0_);                  \
    S[1] = *reinterpret_cast<const float4*>(p0_ + 4);              \
    S[2] = *reinterpret_cast<const float4*>(p0_ + 8);              \
    S[3] = *reinterpret_cast<const float4*>(p0_ + 12);             \
    S[4] = *reinterpret_cast<const float4*>(p1_);                  \
    S[5] = *reinterpret_cast<const float4*>(p1_ + 4);              \
    S[6] = *reinterpret_cast<const float4*>(p1_ + 8);              \
    S[7] = *reinterpret_cast<const float4*>(p1_ + 12); }

#define GQ_STAGEB(KT, BUF)                                                         \
  { _Pragma("unroll")                                                              \
    for (int i_ = 0; i_ < 4; ++i_) {                                               \
      int c_ = w * 4 + i_;                                                         \
      int ch_ = ((KT) * 2 + (c_ >> 3)) * 32 + nq * 8 + (c_ & 7);                   \
      gload_lds16(W1c + (((size_t)ch_ * 64 + l) << 4),                             \
                  BbC + (size_t)(BUF) * 16384 + (c_ << 10));                       \
    } }

#define GQ_PACK4(D, A, B)                                          \
  { D.u4[0] = pack2bf(A.x, A.y); D.u4[1] = pack2bf(A.z, A.w);      \
    D.u4[2] = pack2bf(B.x, B.y); D.u4[3] = pack2bf(B.z, B.w); }

#define GQ_CONVA(S, BUF)                                                      \
  { unsigned short* ab_ = &Ab[BUF][0];                                        \
    union { bf16x8 v; unsigned int u4[4]; } d_;                               \
    GQ_PACK4(d_, S[0], S[1]); *reinterpret_cast<bf16x8*>(ab_ + awi00) = d_.v; \
    GQ_PACK4(d_, S[2], S[3]); *reinterpret_cast<bf16x8*>(ab_ + awi01) = d_.v; \
    GQ_PACK4(d_, S[4], S[5]); *reinterpret_cast<bf16x8*>(ab_ + awi10) = d_.v; \
    GQ_PACK4(d_, S[6], S[7]); *reinterpret_cast<bf16x8*>(ab_ + awi11) = d_.v; }

#define GQ_BODY(KT, LS, CS)                                                   \
  { const int kt_ = (KT);                                                     \
    if (kt_ + 2 < 32) GQ_LOADA(LS, kt_ + 2);                                  \
    if (kt_ + 1 < 32) {                                                       \
      GQ_STAGEB(kt_ + 1, (kt_ + 1) & 1);                                      \
      GQ_CONVA(CS, (kt_ + 1) & 1);                                            \
    }                                                                         \
    _Pragma("unroll")                                                         \
    for (int ks_ = 0; ks_ < 2; ++ks_) {                                       \
      bf16x8 af0_ = *reinterpret_cast<const bf16x8*>(                         \
          &Ab[kt_ & 1][((ks_ * 8 + 2 * w) * 64 + l) * 8]);                    \
      bf16x8 af1_ = *reinterpret_cast<const bf16x8*>(                         \
          &Ab[kt_ & 1][((ks_ * 8 + 2 * w + 1) * 64 + l) * 8]);                \
      _Pragma("unroll")                                                       \
      for (int ct_ = 0; ct_ < 8; ++ct_) {                                     \
        bf16x8 bfr_ = *reinterpret_cast<const bf16x8*>(                       \
            &Bb[kt_ & 1][((ks_ * 8 + ct_) * 64 + l) * 8]);                    \
        acc[0][ct_] = __builtin_amdgcn_mfma_f32_16x16x32_bf16(af0_, bfr_, acc[0][ct_], 0, 0, 0); \
        acc[1][ct_] = __builtin_amdgcn_mfma_f32_16x16x32_bf16(af1_, bfr_, acc[1][ct_], 0, 0, 0); \
      }                                                                       \
    }                                                                         \
    __syncthreads();                                                          \
  }

__launch_bounds__(256, 2)
__global__ void k_gemm1q(const float* __restrict__ features,
                         const unsigned short* __restrict__ W1s,
                         const float* __restrict__ hproj,
                         const float* __restrict__ b1,
                         const float* __restrict__ V,
                         float* __restrict__ partials) {
  __shared__ unsigned short Ab[2][8192];   // 2 x 16 KB [ks(2)][rtg(8)][lane][8]
  __shared__ unsigned short Bb[2][8192];   // 2 x 16 KB [ks(2)][slot(8)][lane][8]
  __shared__ float wlog[4][32];

  int t = threadIdx.x, w = t >> 6, l = t & 63;
  int bid = blockIdx.x;
  int swz = (bid & 7) * 64 + (bid >> 3);   // bijective, 512 = 8*64; 4 nq of same mb2 per XCD
  int nq = swz & 3;                         // 128-col quarter
  int mb2 = swz >> 2;                       // 128-row tile (2 batches)

  f32x4 acc[2][8];
#pragma unroll
  for (int rt = 0; rt < 2; ++rt)
#pragma unroll
    for (int ct = 0; ct < 8; ++ct) acc[rt][ct] = (f32x4){0.f, 0.f, 0.f, 0.f};

  // A staging: thread t -> chunks (row r0=t>>2, q=t&3: 16 f32) and (row r0+64, same q)
  int r0 = t >> 2, q = t & 3;
  const float* Ap0 = features + (size_t)(mb2 * 128 + r0) * FEAT_N + q * 16;
  const float* Ap1 = Ap0 + (size_t)64 * FEAT_N;
  int ks0 = q >> 1, lq0 = (q & 1) * 2;
  int rtg0 = r0 >> 4, lr0 = r0 & 15;
  const int awi00 = ((ks0 * 8 + rtg0) * 64 + lq0 * 16 + lr0) * 8;
  const int awi01 = awi00 + 128;    // lq0+1
  const int awi10 = awi00 + 2048;   // rtg0+4 (row+64)
  const int awi11 = awi01 + 2048;
  const char* W1c = (const char*)W1s;
  char* BbC = (char*)Bb;

  float4 aS[8], bS[8];

  // prologue: A(0)->aS, A(1)->bS, B(0)->buf0, convert A(0)->buf0
  GQ_LOADA(aS, 0);
  GQ_LOADA(bS, 1);
  GQ_STAGEB(0, 0);
  GQ_CONVA(aS, 0);
  __syncthreads();

  for (int kt2 = 0; kt2 < 32; kt2 += 2) {
    GQ_BODY(kt2, aS, bS);       // load A(kt2+2)->aS; convert A(kt2+1)=bS
    GQ_BODY(kt2 + 1, bS, aS);   // load A(kt2+3)->bS; convert A(kt2+2)=aS
  }

  // epilogue: partial logits over this quarter's 128 cols
  int bw = mb2 * 2 + (w >> 1);              // batch owning this wave's 32 rows
  float rowpart[8];
#pragma unroll
  for (int i = 0; i < 8; ++i) rowpart[i] = 0.f;
#pragma unroll
  for (int ct = 0; ct < 8; ++ct) {
    int col = nq * 128 + ct * 16 + (l & 15);
    float hb = hproj[(size_t)bw * UNITS_N + col] + b1[col];
    float vv = V[col];
#pragma unroll
    for (int rti = 0; rti < 2; ++rti)
#pragma unroll
      for (int i = 0; i < 4; ++i)
        rowpart[rti * 4 + i] += tanhf(acc[rti][ct][i] + hb) * vv;
  }
#pragma unroll
  for (int m = 1; m <= 8; m <<= 1)
#pragma unroll
    for (int i = 0; i < 8; ++i) rowpart[i] += __shfl_xor(rowpart[i], m, 64);
  if ((l & 15) == 0) {
    int g = l >> 4;
#pragma unroll
    for (int rti = 0; rti < 2; ++rti)
#pragma unroll
      for (int i = 0; i < 4; ++i)
        wlog[w][rti * 16 + g * 4 + i] = rowpart[rti * 4 + i];
  }
  __syncthreads();
  if (t < 128) {
    int bl = t >> 6, rr = t & 63;
    int R = bl * 64 + rr;                   // row within 128-row tile
    float x = wlog[R >> 5][R & 31];
    partials[nq * 16384 + (mb2 * 2 + bl) * 64 + rr] = x;
  }
}

// ---- softmax (nsets partials) + context + tanh-concat frags; 2 batches per block
__global__ void k_context(const float* __restrict__ features,
                          const float* __restrict__ partials,
                          const float* __restrict__ hidden,
                          unsigned short* __restrict__ tcfrag,
                          float* __restrict__ attn_out, int nsets) {
  __shared__ float aL[2][64];
  int t = threadIdx.x;           // 0..1023
  int half = t >> 9, tt = t & 511;
  int b = blockIdx.x * 2 + half;
  if (tt < 64) {
    float x = 0.f;
    for (int p = 0; p < nsets; ++p) x += partials[p * 16384 + b * 64 + tt];
    float mx = x;
#pragma unroll
    for (int m = 1; m < 64; m <<= 1) mx = fmaxf(mx, __shfl_xor(mx, m, 64));
    float e = __expf(x - mx);
    float s = e;
#pragma unroll
    for (int m = 1; m < 64; m <<= 1) s += __shfl_xor(s, m, 64);
    float a = e / s;
    aL[half][tt] = a;
    attn_out[(size_t)b * 64 + tt] = a;
  }
  __syncthreads();
  const float* F = features + (size_t)b * 64 * FEAT_N + tt * 4;
  float a0 = 0.f, a1 = 0.f, a2 = 0.f, a3 = 0.f;
#pragma unroll 4
  for (int lr = 0; lr < 64; ++lr) {
    float4 f = *reinterpret_cast<const float4*>(F + (size_t)lr * FEAT_N);
    float av = aL[half][lr];
    a0 += av * f.x; a1 += av * f.y; a2 += av * f.z; a3 += av * f.w;
  }
  store_frag4(tcfrag, 80, b, tt * 4, tanhf(a0), tanhf(a1), tanhf(a2), tanhf(a3));
  if (tt < 128) {
    const float* H = hidden + (size_t)b * UNITS_N + tt * 4;
    store_frag4(tcfrag, 80, b, 2048 + tt * 4, tanhf(H[0]), tanhf(H[1]), tanhf(H[2]), tanhf(H[3]));
  }
}

// ---- fc2: grid (500, 2)
__launch_bounds__(256)
__global__ void k_fc2(const unsigned short* __restrict__ x1frag,
                      const float* __restrict__ W, const float* __restrict__ bias,
                      float* __restrict__ out) {
  __shared__ unsigned short Bb[4 * 64 * 8];
  int t = threadIdx.x, w = t >> 6, l = t & 63;
  int n0 = blockIdx.x * 64;
  int mh = blockIdx.y;
  f32x4 acc[2][4];
#pragma unroll
  for (int r = 0; r < 2; ++r)
#pragma unroll
    for (int c = 0; c < 4; ++c) acc[r][c] = (f32x4){0.f, 0.f, 0.f, 0.f};

  int sn = t & 63, kc = t >> 6;
  unsigned short* wdst = &Bb[(((sn >> 4) * 64) + ((sn & 15) | (kc << 4))) * 8];
  const float* Wp = W + n0 + sn;
  float wreg[8];
#pragma unroll
  for (int j = 0; j < 8; ++j) wreg[j] = Wp[(size_t)(kc * 8 + j) * VOCAB_N];

  for (int kt = 0; kt < 16; ++kt) {
    __syncthreads();
    {
      union { bf16x8 v; unsigned short s[8]; } p;
#pragma unroll
      for (int j = 0; j < 8; ++j) p.s[j] = f2bf(wreg[j]);
      *reinterpret_cast<bf16x8*>(wdst) = p.v;
    }
    __syncthreads();
    if (kt < 15) {
#pragma unroll
      for (int j = 0; j < 8; ++j) wreg[j] = Wp[(size_t)((kt + 1) * 32 + kc * 8 + j) * VOCAB_N];
    }
    bf16x8 bf[4];
#pragma unroll
    for (int c = 0; c < 4; ++c) bf[c] = *reinterpret_cast<const bf16x8*>(&Bb[((c * 64) + l) * 8]);
#pragma unroll
    for (int rti = 0; rti < 2; ++rti) {
      int rtg = mh * 8 + w * 2 + rti;
      bf16x8 af = *reinterpret_cast<const bf16x8*>(x1frag + ((size_t)(rtg * 16 + kt) * 64 + l) * 8);
#pragma unroll
      for (int c = 0; c < 4; ++c)
        acc[rti][c] = __builtin_amdgcn_mfma_f32_16x16x32_bf16(af, bf[c], acc[rti][c], 0, 0, 0);
    }
  }
#pragma unroll
  for (int c = 0; c < 4; ++c) {
    int col = n0 + c * 16 + (l & 15);
    float bv = bias[col];
#pragma unroll
    for (int rti = 0; rti < 2; ++rti)
#pragma unroll
      for (int i = 0; i < 4; ++i) {
        int row = mh * 128 + w * 32 + rti * 16 + (l >> 4) * 4 + i;
        out[(size_t)row * VOCAB_N + col] = acc[rti][c][i] + bv;
      }
  }
}

extern "C" void kernel_launch(void* const* d_in, const int* in_sizes, int n_in,
                              void* d_out, int out_size, void* d_ws, size_t ws_size,
                              hipStream_t stream) {
  const int*   tok        = (const int*)d_in[0];
  const float* features   = (const float*)d_in[1];
  const float* hidden     = (const float*)d_in[2];
  const float* W1         = (const float*)d_in[3];
  const float* b1         = (const float*)d_in[4];
  const float* W2         = (const float*)d_in[5];
  const float* b2         = (const float*)d_in[6];
  const float* V          = (const float*)d_in[7];
  // d_in[8] = bV: cancels in softmax
  const float* W3         = (const float*)d_in[9];
  const float* b3         = (const float*)d_in[10];
  const float* emb_table  = (const float*)d_in[11];
  const float* gru_kernel = (const float*)d_in[12];
  // d_in[13] = gru_rec: unused (h0 == 0); r-gate columns of gru_kernel also dead
  const float* gru_bias   = (const float*)d_in[14];
  const float* fc1_W      = (const float*)d_in[15];
  const float* fc1_b      = (const float*)d_in[16];
  const float* fc2_W      = (const float*)d_in[17];
  const float* fc2_b      = (const float*)d_in[18];

  float* out_logits = (float*)d_out;
  float* out_h      = out_logits + (size_t)B_N * VOCAB_N;
  float* out_attn   = out_h + (size_t)B_N * UNITS_N;

  char* ws = (char*)d_ws;
  unsigned short* W1s     = (unsigned short*)(ws);               // 2,097,152
  float*          hproj   = (float*)(ws + 2097152);              //   524,288
  unsigned short* hfrag   = (unsigned short*)(ws + 2621440);     //   262,144
  unsigned short* tcfrag  = (unsigned short*)(ws + 2883584);     // 1,310,720
  unsigned short* xinfrag = (unsigned short*)(ws + 4194304);     //   393,216
  unsigned short* hnfrag  = (unsigned short*)(ws + 4587520);     //   262,144
  unsigned short* x1frag  = (unsigned short*)(ws + 4849664);     //   262,144
  unsigned short* W2f     = (unsigned short*)(ws + 5242880);     //   524,288
  unsigned short* W3f     = (unsigned short*)(ws + 5767168);     // 2,621,440
  unsigned short* gruf    = (unsigned short*)(ws + 8388608);     // 1,572,864
  unsigned short* fc1f    = (unsigned short*)(ws + 9961472);     //   524,288
  float*          partials= (float*)(ws + 10485760);             //   262,144 (4 sets)

  k_prep_all<<<dim3(1984), dim3(256), 0, stream>>>(W1, W1s, hidden, emb_table, tok,
                                                   hfrag, xinfrag, W2, W2f, W3, W3f,
                                                   gru_kernel, gruf, fc1_W, fc1f);
  // hproj = hidden @ W2 + b2
  k_small2<0><<<dim3(8, 8), dim3(256), 0, stream>>>(hfrag, 16, W2f, b2, hproj, 512,
                                                    (unsigned short*)nullptr, 0);
  // partial logits (fat-step pipeline)
  k_gemm1q<<<dim3(512), dim3(256), 0, stream>>>(features, W1s, hproj, b1, V, partials);
  // softmax + context + tanh-concat frags
  k_context<<<dim3(128), dim3(1024), 0, stream>>>(features, partials, hidden, tcfrag,
                                                  out_attn, 4);
  // cvh = tc @ W3 + b3 -> xin frags
  k_small2<1><<<dim3(8, 8), dim3(256), 0, stream>>>(tcfrag, 80, W3f, b3, (float*)nullptr, 0,
                                                    xinfrag, 24);
  // gru: z/hh GEMM fused with activation -> out_h + hn frags
  k_small2<2><<<dim3(8, 8), dim3(256), 0, stream>>>(xinfrag, 24, gruf, gru_bias, out_h, 512,
                                                    hnfrag, 16);
  // x1 = h_new @ fc1_W + fc1_b -> frags
  k_small2<1><<<dim3(8, 8), dim3(256), 0, stream>>>(hnfrag, 16, fc1f, fc1_b, (float*)nullptr, 0,
                                                    x1frag, 16);
  // logits_out = x1 @ fc2_W + fc2_b
  k_fc2<<<dim3(500, 2), dim3(256), 0, stream>>>(x1frag, fc2_W, fc2_b, out_logits);
}

// Round 14
// 154.219 us; speedup vs baseline: 1.4673x; 1.0142x over previous
//
#include <hip/hip_runtime.h>
#include <hip/hip_bf16.h>

#define B_N 256
#define L_Q 64
#define FEAT_N 2048
#define UNITS_N 512
#define EMB_N 256
#define VOCAB_N 32000

typedef __attribute__((ext_vector_type(8))) short bf16x8;
typedef __attribute__((ext_vector_type(4))) float f32x4;

__device__ __forceinline__ unsigned short f2bf(float x) {
  union { float f; unsigned int u; } c; c.f = x;
  unsigned int u = c.u + 0x7FFFu + ((c.u >> 16) & 1u);
  return (unsigned short)(u >> 16);
}

// pack two f32 -> u32 of 2 bf16 (round-half-up, 2 VALU ops)
__device__ __forceinline__ unsigned int pack2bf(float a, float b) {
  union { float f; unsigned int u; } x, y; x.f = a; y.f = b;
  return ((y.u + 0x8000u) & 0xFFFF0000u) | ((x.u + 0x8000u) >> 16);
}

__device__ __forceinline__ float sigmoidf_(float x) { return 1.0f / (1.0f + __expf(-x)); }

// A-fragment layout for mfma_f32_16x16x32_bf16 (KS = K/32):
//   ushort index = ((rt*KS + ks)*64 + (lq*16+lr))*8 + j ; row = rt*16+lr, k = ks*32+lq*8+j
__device__ __forceinline__ void store_frag4(unsigned short* base, int KS, int row, int k0,
                                            float a, float b, float c, float d) {
  int rt = row >> 4, lr = row & 15;
  int ks = k0 >> 5, lq = (k0 >> 3) & 3, j0 = k0 & 7;
  union { unsigned long long u; unsigned short s[4]; } p;
  p.s[0] = f2bf(a); p.s[1] = f2bf(b); p.s[2] = f2bf(c); p.s[3] = f2bf(d);
  *reinterpret_cast<unsigned long long*>(base + (((rt * KS + ks) * 64) + (lq * 16 + lr)) * 8 + j0) = p.u;
}

__device__ __forceinline__ void gload_lds16(const void* g, void* lds) {
  __builtin_amdgcn_global_load_lds(
      (const __attribute__((address_space(1))) unsigned int*)(uintptr_t)g,
      (__attribute__((address_space(3))) unsigned int*)(unsigned)(uintptr_t)lds,
      16, 0, 0);
}

// B-fragment weight layout: idx = (((nt*4+ct)*KS + ks)*64 + l)*8 + j
__device__ __forceinline__ void wfrag_one(const float* __restrict__ W, int N, int KS,
                                          unsigned short* __restrict__ dst, int tid, int gruMap) {
  int l = tid & 63;
  int ks = (tid >> 6) % KS;
  int cts = tid / (64 * KS);
  int ct = cts & 3, nt = cts >> 2;
  int nb = gruMap ? (nt < 8 ? nt * 64 : 1024 + (nt - 8) * 64) : nt * 64;
  int ncol = nb + ct * 16 + (l & 15);
  int k0 = ks * 32 + (l >> 4) * 8;
  union { bf16x8 v; unsigned short s[8]; } fr;
#pragma unroll
  for (int j = 0; j < 8; ++j) fr.s[j] = f2bf(W[(size_t)(k0 + j) * N + ncol]);
  *reinterpret_cast<bf16x8*>(dst + (size_t)tid * 8) = fr.v;
}

// ---- fused prep (lean)
__global__ void k_prep_all(const float* __restrict__ W1, unsigned short* __restrict__ W1s,
                           const float* __restrict__ hidden,
                           const float* __restrict__ emb_table,
                           const int* __restrict__ tok,
                           unsigned short* __restrict__ hfrag,
                           unsigned short* __restrict__ xinfrag,
                           const float* __restrict__ W2, unsigned short* __restrict__ W2f,
                           const float* __restrict__ W3, unsigned short* __restrict__ W3f,
                           const float* __restrict__ gruK, unsigned short* __restrict__ gruf,
                           const float* __restrict__ fc1W, unsigned short* __restrict__ fc1f) {
  int bb = blockIdx.x;
  if (bb < 512) {
    int t = bb * 256 + threadIdx.x;
    int l = t & 63;
    int c = (t >> 6) & 31;
    int kt = t >> 11;
    int n = c * 16 + (l & 15);
    int k0 = kt * 32 + (l >> 4) * 8;
    union { bf16x8 v; unsigned short s[8]; } fr;
#pragma unroll
    for (int j = 0; j < 8; ++j) fr.s[j] = f2bf(W1[(size_t)(k0 + j) * UNITS_N + n]);
    *reinterpret_cast<bf16x8*>(W1s + (size_t)t * 8) = fr.v;
  } else if (bb < 704) {
    int t = (bb - 512) * 256 + threadIdx.x;
    if (t < 32768) {
      int b = t >> 7, k0 = (t & 127) * 4;
      const float* s = hidden + (size_t)b * UNITS_N + k0;
      store_frag4(hfrag, 16, b, k0, s[0], s[1], s[2], s[3]);
    } else if (t < 49152) {
      int t2 = t - 32768;
      int b = t2 >> 6, e0 = (t2 & 63) * 4;
      const float* s = emb_table + (size_t)tok[b] * EMB_N + e0;
      store_frag4(xinfrag, 24, b, 512 + e0, s[0], s[1], s[2], s[3]);
    }
  } else if (bb < 832) {
    wfrag_one(W2, 512, 16, W2f, (bb - 704) * 256 + threadIdx.x, 0);
  } else if (bb < 1472) {
    wfrag_one(W3, 512, 80, W3f, (bb - 832) * 256 + threadIdx.x, 0);
  } else if (bb < 1856) {
    wfrag_one(gruK, 1536, 24, gruf, (bb - 1472) * 256 + threadIdx.x, 1);
  } else {
    wfrag_one(fc1W, 512, 16, fc1f, (bb - 1856) * 256 + threadIdx.x, 0);
  }
}

// ---- split-K small GEMM (unchanged, proven)
template <int MODE>
__launch_bounds__(256)
__global__ void k_small2(const unsigned short* __restrict__ Afrag, int KS,
                         const unsigned short* __restrict__ Bfrag,
                         const float* __restrict__ bias,
                         float* __restrict__ outF, int N,
                         unsigned short* __restrict__ outFrag, int KSo) {
  constexpr int NCT = (MODE == 2) ? 8 : 4;
  __shared__ f32x4 red[4][2][NCT][64];
  int t = threadIdx.x, w = t >> 6, l = t & 63;
  int nt = blockIdx.x;
  int mb = blockIdx.y;
  int KSq = KS >> 2;

  f32x4 acc[2][NCT];
#pragma unroll
  for (int rt = 0; rt < 2; ++rt)
#pragma unroll
    for (int ct = 0; ct < NCT; ++ct) acc[rt][ct] = (f32x4){0.f, 0.f, 0.f, 0.f};

  for (int s = 0; s < KSq; ++s) {
    int ks = w * KSq + s;
    bf16x8 af[2];
#pragma unroll
    for (int rt = 0; rt < 2; ++rt)
      af[rt] = *reinterpret_cast<const bf16x8*>(Afrag + (((size_t)(mb * 2 + rt) * KS + ks) * 64 + l) * 8);
#pragma unroll
    for (int ct = 0; ct < NCT; ++ct) {
      int tile = (MODE == 2) ? (ct < 4 ? nt : 8 + nt) : nt;
      int cts = ct & 3;
      bf16x8 bf = *reinterpret_cast<const bf16x8*>(Bfrag + (((size_t)(tile * 4 + cts) * KS + ks) * 64 + l) * 8);
#pragma unroll
      for (int rt = 0; rt < 2; ++rt)
        acc[rt][ct] = __builtin_amdgcn_mfma_f32_16x16x32_bf16(af[rt], bf, acc[rt][ct], 0, 0, 0);
    }
  }

#pragma unroll
  for (int rt = 0; rt < 2; ++rt)
#pragma unroll
    for (int ct = 0; ct < NCT; ++ct) red[w][rt][ct][l] = acc[rt][ct];
  __syncthreads();

#pragma unroll
  for (int si = 0; si < 2; ++si) {
    int s = t + si * 256;
    int l2 = s & 63, ct = (s >> 6) & 3, rt = s >> 8;
    f32x4 v = red[0][rt][ct][l2];
#pragma unroll
    for (int ww = 1; ww < 4; ++ww) v += red[ww][rt][ct][l2];
    int col = nt * 64 + ct * 16 + (l2 & 15);
    int row0 = mb * 32 + rt * 16 + (l2 >> 4) * 4;
    if (MODE == 2) {
      f32x4 vh = red[0][rt][ct + 4][l2];
#pragma unroll
      for (int ww = 1; ww < 4; ++ww) vh += red[ww][rt][ct + 4][l2];
      float bz = bias[col], bh = bias[1024 + col];
#pragma unroll
      for (int i = 0; i < 4; ++i) {
        float hv = (1.f - sigmoidf_(v[i] + bz)) * tanhf(vh[i] + bh);
        int row = row0 + i;
        outF[(size_t)row * UNITS_N + col] = hv;
        int k = col;
        outFrag[(((size_t)(row >> 4) * KSo + (k >> 5)) * 64 + (((k >> 3) & 3) * 16 + (row & 15))) * 8 + (k & 7)] = f2bf(hv);
      }
    } else {
      float bv = bias[col];
#pragma unroll
      for (int i = 0; i < 4; ++i) {
        float vv = v[i] + bv;
        int row = row0 + i;
        if (MODE == 0) {
          outF[(size_t)row * N + col] = vv;
        } else {
          int k = col;
          outFrag[(((size_t)(row >> 4) * KSo + (k >> 5)) * 64 + (((k >> 3) & 3) * 16 + (row & 15))) * 8 + (k & 7)] = f2bf(vv);
        }
      }
    }
  }
}

// ==== GEMM1v: counted-vmcnt pipeline (no vmcnt(0) in loop, raw s_barrier) ====
// BM=64, BN=128, BK=32, 64 steps; 3-deep LDS ring (A f32 8KB XOR-swizzled + B bf16 8KB
// per buffer = 48KB -> 3 blocks/CU). Per step: issue 4 global_load_lds for kt+1 ->
// s_waitcnt vmcnt(4) (kt's loads complete, kt+1's stay IN FLIGHT across the barrier)
// -> s_barrier -> convert A at consume time (pack2bf) + 8 MFMA/wave.
// Ring-3 is WAR-safe at <=1-barrier wave skew: writer (kt+1)%3 vs slowest reader
// (kt-1)%3 differ by 2. A swizzle: LDS slot p holds global chunk (p&7)^((p>>3)&7)
// (involution, applied on both stage-source and ds_read sides -> 2-way conflicts only).

#define GV_STAGE(KT, BUF)                                                          \
  { gload_lds16(gA0 + (size_t)(KT) * 32, AfC + (BUF) * 8192 + t * 16);             \
    gload_lds16(gA1 + (size_t)(KT) * 32, AfC + (BUF) * 8192 + (t + 256) * 16);     \
    gload_lds16(gB0 + (size_t)(KT) * 16384, BbC + (BUF) * 8192 + t * 16);          \
    gload_lds16(gB1 + (size_t)(KT) * 16384, BbC + (BUF) * 8192 + (t + 256) * 16); }

#define GV_COMP(KT, BUF)                                                           \
  { f32x4 x0_ = *reinterpret_cast<const f32x4*>(&Af[BUF][ari0]);                   \
    f32x4 x1_ = *reinterpret_cast<const f32x4*>(&Af[BUF][ari1]);                   \
    union { bf16x8 v; unsigned int u4[4]; } uf_;                                   \
    uf_.u4[0] = pack2bf(x0_[0], x0_[1]); uf_.u4[1] = pack2bf(x0_[2], x0_[3]);      \
    uf_.u4[2] = pack2bf(x1_[0], x1_[1]); uf_.u4[3] = pack2bf(x1_[2], x1_[3]);      \
    bf16x8 af_ = uf_.v;                                                            \
    _Pragma("unroll")                                                              \
    for (int ct_ = 0; ct_ < 8; ++ct_) {                                            \
      bf16x8 bf_ = *reinterpret_cast<const bf16x8*>(&Bb[BUF][(ct_ * 64 + l) * 8]); \
      acc[ct_] = __builtin_amdgcn_mfma_f32_16x16x32_bf16(af_, bf_, acc[ct_], 0, 0, 0); \
    } }

#define GV_BODY(KT, BUFC, BUFS)                                                    \
  { GV_STAGE((KT) + 1, BUFS);                                                      \
    asm volatile("s_waitcnt vmcnt(4)" ::: "memory");                               \
    __builtin_amdgcn_s_barrier();                                                  \
    __builtin_amdgcn_sched_barrier(0);                                             \
    GV_COMP(KT, BUFC); }

__launch_bounds__(256, 3)
__global__ void k_gemm1v(const float* __restrict__ features,
                         const unsigned short* __restrict__ W1s,
                         const float* __restrict__ hproj,
                         const float* __restrict__ b1,
                         const float* __restrict__ V,
                         float* __restrict__ partials) {
  __shared__ float Af[3][2048];            // 3 x 8 KB (f32 A-tile, XOR-swizzled chunks)
  __shared__ unsigned short Bb[3][4096];   // 3 x 8 KB (bf16 B frags, linear)
  __shared__ float wlog[4][16];

  int t = threadIdx.x, w = t >> 6, l = t & 63;
  int bid = blockIdx.x;
  int swz = (bid & 7) * 128 + (bid >> 3);  // bijective, 1024 = 8*128; 4 nq of same mb per XCD
  int nq = swz & 3;                         // 128-col quarter
  int mb = swz >> 2;                        // batch (64 rows)

  f32x4 acc[8];
#pragma unroll
  for (int ct = 0; ct < 8; ++ct) acc[ct] = (f32x4){0.f, 0.f, 0.f, 0.f};

  // Stage source pointers (pre-swizzled global A; linear B from frag-ordered W1s).
  // A slot p (16B): row = p>>3, c_lds = p&7, c_global = c_lds ^ (row&7).
  int s0 = t, s1 = t + 256;
  int r0 = s0 >> 3, cg0 = (s0 & 7) ^ (r0 & 7);
  int r1 = s1 >> 3, cg1 = (s1 & 7) ^ (r1 & 7);
  const float* gA0 = features + (size_t)(mb * 64 + r0) * FEAT_N + cg0 * 4;
  const float* gA1 = features + (size_t)(mb * 64 + r1) * FEAT_N + cg1 * 4;
  // B slot s: chunk slot cs = s>>6, lane = s&63; chunk ch = kt*32 + nq*8 + cs.
  const unsigned short* gB0 = W1s + ((size_t)(nq * 8 + (t >> 6)) * 64 + (t & 63)) * 8;
  const unsigned short* gB1 = W1s + ((size_t)(nq * 8 + (t >> 6) + 4) * 64 + (t & 63)) * 8;
  char* AfC = (char*)Af;
  char* BbC = (char*)Bb;

  // Compute-side A read indices (f32): row rl, chunks c0,c0+1 swizzled by rl&7.
  int rl = w * 16 + (l & 15);
  int c0 = (l >> 4) * 2;
  const int ari0 = (rl * 8 + (c0 ^ (rl & 7))) * 4;
  const int ari1 = (rl * 8 + ((c0 + 1) ^ (rl & 7))) * 4;

  // prologue: stage step 0 into buf 0
  GV_STAGE(0, 0);

  for (int kt = 0; kt < 63; kt += 3) {
    GV_BODY(kt, 0, 1);
    GV_BODY(kt + 1, 1, 2);
    GV_BODY(kt + 2, 2, 0);
  }
  // tail: step 63 (buf 0), no further stage
  asm volatile("s_waitcnt vmcnt(0)" ::: "memory");
  __builtin_amdgcn_s_barrier();
  __builtin_amdgcn_sched_barrier(0);
  GV_COMP(63, 0);

  // epilogue: partial logits over this quarter's 128 cols
  float rowpart[4];
#pragma unroll
  for (int i = 0; i < 4; ++i) rowpart[i] = 0.f;
#pragma unroll
  for (int ct = 0; ct < 8; ++ct) {
    int col = nq * 128 + ct * 16 + (l & 15);
    float hb = hproj[(size_t)mb * UNITS_N + col] + b1[col];
    float vv = V[col];
#pragma unroll
    for (int i = 0; i < 4; ++i)
      rowpart[i] += tanhf(acc[ct][i] + hb) * vv;
  }
#pragma unroll
  for (int m = 1; m <= 8; m <<= 1)
#pragma unroll
    for (int i = 0; i < 4; ++i) rowpart[i] += __shfl_xor(rowpart[i], m, 64);
  if ((l & 15) == 0) {
    int g = l >> 4;
#pragma unroll
    for (int i = 0; i < 4; ++i) wlog[w][g * 4 + i] = rowpart[i];
  }
  __syncthreads();
  if (t < 64)
    partials[nq * 16384 + mb * 64 + t] = wlog[t >> 4][t & 15];
}

// ---- softmax (nsets partials) + context + tanh-concat frags; 2 batches per block
__global__ void k_context(const float* __restrict__ features,
                          const float* __restrict__ partials,
                          const float* __restrict__ hidden,
                          unsigned short* __restrict__ tcfrag,
                          float* __restrict__ attn_out, int nsets) {
  __shared__ float aL[2][64];
  int t = threadIdx.x;           // 0..1023
  int half = t >> 9, tt = t & 511;
  int b = blockIdx.x * 2 + half;
  if (tt < 64) {
    float x = 0.f;
    for (int p = 0; p < nsets; ++p) x += partials[p * 16384 + b * 64 + tt];
    float mx = x;
#pragma unroll
    for (int m = 1; m < 64; m <<= 1) mx = fmaxf(mx, __shfl_xor(mx, m, 64));
    float e = __expf(x - mx);
    float s = e;
#pragma unroll
    for (int m = 1; m < 64; m <<= 1) s += __shfl_xor(s, m, 64);
    float a = e / s;
    aL[half][tt] = a;
    attn_out[(size_t)b * 64 + tt] = a;
  }
  __syncthreads();
  const float* F = features + (size_t)b * 64 * FEAT_N + tt * 4;
  float a0 = 0.f, a1 = 0.f, a2 = 0.f, a3 = 0.f;
#pragma unroll 4
  for (int lr = 0; lr < 64; ++lr) {
    float4 f = *reinterpret_cast<const float4*>(F + (size_t)lr * FEAT_N);
    float av = aL[half][lr];
    a0 += av * f.x; a1 += av * f.y; a2 += av * f.z; a3 += av * f.w;
  }
  store_frag4(tcfrag, 80, b, tt * 4, tanhf(a0), tanhf(a1), tanhf(a2), tanhf(a3));
  if (tt < 128) {
    const float* H = hidden + (size_t)b * UNITS_N + tt * 4;
    store_frag4(tcfrag, 80, b, 2048 + tt * 4, tanhf(H[0]), tanhf(H[1]), tanhf(H[2]), tanhf(H[3]));
  }
}

// ---- fc2: grid (500, 2)
__launch_bounds__(256)
__global__ void k_fc2(const unsigned short* __restrict__ x1frag,
                      const float* __restrict__ W, const float* __restrict__ bias,
                      float* __restrict__ out) {
  __shared__ unsigned short Bb[4 * 64 * 8];
  int t = threadIdx.x, w = t >> 6, l = t & 63;
  int n0 = blockIdx.x * 64;
  int mh = blockIdx.y;
  f32x4 acc[2][4];
#pragma unroll
  for (int r = 0; r < 2; ++r)
#pragma unroll
    for (int c = 0; c < 4; ++c) acc[r][c] = (f32x4){0.f, 0.f, 0.f, 0.f};

  int sn = t & 63, kc = t >> 6;
  unsigned short* wdst = &Bb[(((sn >> 4) * 64) + ((sn & 15) | (kc << 4))) * 8];
  const float* Wp = W + n0 + sn;
  float wreg[8];
#pragma unroll
  for (int j = 0; j < 8; ++j) wreg[j] = Wp[(size_t)(kc * 8 + j) * VOCAB_N];

  for (int kt = 0; kt < 16; ++kt) {
    __syncthreads();
    {
      union { bf16x8 v; unsigned short s[8]; } p;
#pragma unroll
      for (int j = 0; j < 8; ++j) p.s[j] = f2bf(wreg[j]);
      *reinterpret_cast<bf16x8*>(wdst) = p.v;
    }
    __syncthreads();
    if (kt < 15) {
#pragma unroll
      for (int j = 0; j < 8; ++j) wreg[j] = Wp[(size_t)((kt + 1) * 32 + kc * 8 + j) * VOCAB_N];
    }
    bf16x8 bf[4];
#pragma unroll
    for (int c = 0; c < 4; ++c) bf[c] = *reinterpret_cast<const bf16x8*>(&Bb[((c * 64) + l) * 8]);
#pragma unroll
    for (int rti = 0; rti < 2; ++rti) {
      int rtg = mh * 8 + w * 2 + rti;
      bf16x8 af = *reinterpret_cast<const bf16x8*>(x1frag + ((size_t)(rtg * 16 + kt) * 64 + l) * 8);
#pragma unroll
      for (int c = 0; c < 4; ++c)
        acc[rti][c] = __builtin_amdgcn_mfma_f32_16x16x32_bf16(af, bf[c], acc[rti][c], 0, 0, 0);
    }
  }
#pragma unroll
  for (int c = 0; c < 4; ++c) {
    int col = n0 + c * 16 + (l & 15);
    float bv = bias[col];
#pragma unroll
    for (int rti = 0; rti < 2; ++rti)
#pragma unroll
      for (int i = 0; i < 4; ++i) {
        int row = mh * 128 + w * 32 + rti * 16 + (l >> 4) * 4 + i;
        out[(size_t)row * VOCAB_N + col] = acc[rti][c][i] + bv;
      }
  }
}

extern "C" void kernel_launch(void* const* d_in, const int* in_sizes, int n_in,
                              void* d_out, int out_size, void* d_ws, size_t ws_size,
                              hipStream_t stream) {
  const int*   tok        = (const int*)d_in[0];
  const float* features   = (const float*)d_in[1];
  const float* hidden     = (const float*)d_in[2];
  const float* W1         = (const float*)d_in[3];
  const float* b1         = (const float*)d_in[4];
  const float* W2         = (const float*)d_in[5];
  const float* b2         = (const float*)d_in[6];
  const float* V          = (const float*)d_in[7];
  // d_in[8] = bV: cancels in softmax
  const float* W3         = (const float*)d_in[9];
  const float* b3         = (const float*)d_in[10];
  const float* emb_table  = (const float*)d_in[11];
  const float* gru_kernel = (const float*)d_in[12];
  // d_in[13] = gru_rec: unused (h0 == 0); r-gate columns of gru_kernel also dead
  const float* gru_bias   = (const float*)d_in[14];
  const float* fc1_W      = (const float*)d_in[15];
  const float* fc1_b      = (const float*)d_in[16];
  const float* fc2_W      = (const float*)d_in[17];
  const float* fc2_b      = (const float*)d_in[18];

  float* out_logits = (float*)d_out;
  float* out_h      = out_logits + (size_t)B_N * VOCAB_N;
  float* out_attn   = out_h + (size_t)B_N * UNITS_N;

  char* ws = (char*)d_ws;
  unsigned short* W1s     = (unsigned short*)(ws);               // 2,097,152
  float*          hproj   = (float*)(ws + 2097152);              //   524,288
  unsigned short* hfrag   = (unsigned short*)(ws + 2621440);     //   262,144
  unsigned short* tcfrag  = (unsigned short*)(ws + 2883584);     // 1,310,720
  unsigned short* xinfrag = (unsigned short*)(ws + 4194304);     //   393,216
  unsigned short* hnfrag  = (unsigned short*)(ws + 4587520);     //   262,144
  unsigned short* x1frag  = (unsigned short*)(ws + 4849664);     //   262,144
  unsigned short* W2f     = (unsigned short*)(ws + 5242880);     //   524,288
  unsigned short* W3f     = (unsigned short*)(ws + 5767168);     // 2,621,440
  unsigned short* gruf    = (unsigned short*)(ws + 8388608);     // 1,572,864
  unsigned short* fc1f    = (unsigned short*)(ws + 9961472);     //   524,288
  float*          partials= (float*)(ws + 10485760);             //   262,144 (4 sets)

  k_prep_all<<<dim3(1984), dim3(256), 0, stream>>>(W1, W1s, hidden, emb_table, tok,
                                                   hfrag, xinfrag, W2, W2f, W3, W3f,
                                                   gru_kernel, gruf, fc1_W, fc1f);
  // hproj = hidden @ W2 + b2
  k_small2<0><<<dim3(8, 8), dim3(256), 0, stream>>>(hfrag, 16, W2f, b2, hproj, 512,
                                                    (unsigned short*)nullptr, 0);
  // partial logits (counted-vmcnt pipeline)
  k_gemm1v<<<dim3(1024), dim3(256), 0, stream>>>(features, W1s, hproj, b1, V, partials);
  // softmax + context + tanh-concat frags
  k_context<<<dim3(128), dim3(1024), 0, stream>>>(features, partials, hidden, tcfrag,
                                                  out_attn, 4);
  // cvh = tc @ W3 + b3 -> xin frags
  k_small2<1><<<dim3(8, 8), dim3(256), 0, stream>>>(tcfrag, 80, W3f, b3, (float*)nullptr, 0,
                                                    xinfrag, 24);
  // gru: z/hh GEMM fused with activation -> out_h + hn frags
  k_small2<2><<<dim3(8, 8), dim3(256), 0, stream>>>(xinfrag, 24, gruf, gru_bias, out_h, 512,
                                                    hnfrag, 16);
  // x1 = h_new @ fc1_W + fc1_b -> frags
  k_small2<1><<<dim3(8, 8), dim3(256), 0, stream>>>(hnfrag, 16, fc1f, fc1_b, (float*)nullptr, 0,
                                                    x1frag, 16);
  // logits_out = x1 @ fc2_W + fc2_b
  k_fc2<<<dim3(500, 2), dim3(256), 0, stream>>>(x1frag, fc2_W, fc2_b, out_logits);
}